// Round 12
// baseline (712.757 us; speedup 1.0000x reference)
//
#include <hip/hip_runtime.h>
#include <hip/hip_bf16.h>

// Mamba2 mixer forward, MI355X. B=2, L=2048, D_MODEL=2048, H=64, P=64, N=128,
// G=1, K=4, CHUNK=256. T = 4096 tokens, 16 chunks.
// Round 12: (a) gemm_out8 split-K z=2->4 (grid 512 = 2 blocks/CU: restores
// inter-block latency hiding that 1-block/CU lacked); 4 fp32 partials in the
// four dead 33.5MB regions; add_out sums 4 + RMS scale. (b) fast silu
// (x*rcp(1+exp2(-x*log2e)), 3 inst vs ~20-inst libm expf) at the 286M call
// sites (yfused epilogue, convx). Everything else unchanged.

typedef __attribute__((ext_vector_type(8))) _Float16 f16x8;
typedef __attribute__((ext_vector_type(4))) float f32x4;

#define GLD16(gp, lp) __builtin_amdgcn_global_load_lds( \
    (__attribute__((address_space(1))) void*)(gp),      \
    (__attribute__((address_space(3))) void*)(lp), 16, 0, 0)

__device__ __forceinline__ unsigned short f2h(float v) {
  _Float16 h = (_Float16)v;
  return *reinterpret_cast<unsigned short*>(&h);
}
__device__ __forceinline__ float h2f(unsigned short u) {
  _Float16 h = *reinterpret_cast<_Float16*>(&u);
  return (float)h;
}
// fast silu: x * sigmoid(x); sigmoid via single v_exp + v_rcp (~1ulp approx).
__device__ __forceinline__ float siluf(float x) {
  return x * __builtin_amdgcn_rcpf(1.f + exp2f(x * -1.44269504f));
}

// ===================== prep: dtz (1024) || cast_f16 (8192) || twin (16896) ===
__global__ __launch_bounds__(256) void prep(const float* __restrict__ hs,
                                            const float* __restrict__ Win,
                                            _Float16* __restrict__ Ah,
                                            _Float16* __restrict__ WtH,
                                            float* __restrict__ zf) {
  __shared__ __attribute__((aligned(16))) char smemP[32768];
  const int bid = blockIdx.x;
  const int tid = threadIdx.x;
  if (bid < 1024) {
    // ---- dtz: fp32 dt pre-activation (exact slice)
    float (*Xs)[2048] = reinterpret_cast<float (*)[2048]>(smemP);
    int t0 = bid * 4;
#pragma unroll
    for (int i = 0; i < 8; i++) {
      int e = tid * 4 + i * 1024;
      int tok = e >> 11, k = e & 2047;
      *reinterpret_cast<float4*>(&Xs[tok][k]) =
          *reinterpret_cast<const float4*>(&hs[(long)(t0 + tok) * 2048 + k]);
    }
    __syncthreads();
    int h = tid & 63, tg = tid >> 6;
    float a0 = 0.f, a1 = 0.f, a2 = 0.f, a3 = 0.f;
    const float* wcol = Win + 8448 + h;
    for (int k = 0; k < 2048; k += 4) {
      a0 = fmaf(Xs[tg][k + 0], wcol[(long)(k + 0) * 8512], a0);
      a1 = fmaf(Xs[tg][k + 1], wcol[(long)(k + 1) * 8512], a1);
      a2 = fmaf(Xs[tg][k + 2], wcol[(long)(k + 2) * 8512], a2);
      a3 = fmaf(Xs[tg][k + 3], wcol[(long)(k + 3) * 8512], a3);
    }
    zf[(long)(t0 + tg) * 64 + h] = (a0 + a1) + (a2 + a3);
  } else if (bid < 9216) {
    // ---- cast X -> fp16
    long i = ((long)(bid - 1024) * 256 + tid) * 4;
    float4 v = *reinterpret_cast<const float4*>(hs + i);
    ushort4 u;
    u.x = f2h(v.x); u.y = f2h(v.y); u.z = f2h(v.z); u.w = f2h(v.w);
    *reinterpret_cast<ushort4*>((unsigned short*)Ah + i) = u;
  } else {
    // ---- transpose Win cols [0,8448) -> fp16 [n][k]
    float (*tile)[33] = reinterpret_cast<float (*)[33]>(smemP);
    int i = bid - 9216;
    int c0 = (i % 264) * 32, r0 = (i / 264) * 32;
    int tx = tid & 31, ty = tid >> 5;
#pragma unroll
    for (int j = 0; j < 4; j++)
      tile[ty + j * 8][tx] = Win[(long)(r0 + ty + j * 8) * 8512 + c0 + tx];
    __syncthreads();
#pragma unroll
    for (int j = 0; j < 4; j++) {
      int c = c0 + ty + j * 8, r = r0 + tx;
      WtH[(long)c * 2048 + r] = (_Float16)tile[tx][ty + j * 8];
    }
  }
}

// ===================== in_proj GEMM: 256^2 tile, BK=64, 8-wave 8-phase =======
__global__ __launch_bounds__(512, 2) void gemm_in8(const _Float16* __restrict__ A,
                                                   const _Float16* __restrict__ Bt,
                                                   _Float16* __restrict__ gate,
                                                   float* __restrict__ hbcf,
                                                   float* __restrict__ rparts) {
  __shared__ __attribute__((aligned(128))) char ldsB[131072];
  const int tid = threadIdx.x;
  const int lane = tid & 63;
  const int wv = tid >> 6;
  const int wr = wv >> 2, wc = wv & 3;  // 2 (M) x 4 (N) waves; wave C = 128x64
  const int wg = blockIdx.x;
  const bool rem = wg >= 512;
  int by, bxn, kbase, zz;
  if (!rem) {  // square per-XCD mapping: XCD (wg&7) owns 8(by) x 8(bxn)
    const int xcd = wg & 7, j = wg >> 3;
    by = (xcd >> 2) * 8 + (j >> 3);
    bxn = (xcd & 3) * 8 + (j & 7);
    kbase = 0; zz = 0;
  } else {
    const int idx = wg - 512;
    by = idx & 15; zz = idx >> 4; bxn = 32; kbase = zz * 256;
  }

  const int srow = tid >> 3;
  const int scolg = (tid & 7) ^ (srow & 7);  // inverse-swizzled source col16
  const _Float16* Ab = A + (long)by * 524288 + (long)srow * 2048 + scolg * 8 + kbase;
  const _Float16* Bb = Bt + (long)bxn * 524288 + (long)srow * 2048 + scolg * 8 + kbase;
  const int ldst = tid << 4;

#define STAGE_A(tau, h) do {                                              \
    const _Float16* g_ = Ab + (long)(h) * 262144 + (tau) * 64;            \
    char* l_ = ldsB + ((((tau) & 1) << 2) + (h)) * 16384 + ldst;          \
    GLD16(g_, l_); GLD16(g_ + 131072, l_ + 8192); } while (0)
#define STAGE_B(tau, h) do {                                              \
    const _Float16* g_ = Bb + (long)(h) * 262144 + (tau) * 64;            \
    char* l_ = ldsB + ((((tau) & 1) << 2) + 2 + (h)) * 16384 + ldst;      \
    GLD16(g_, l_); GLD16(g_ + 131072, l_ + 8192); } while (0)

  const int fr = lane & 15;
  const int c16 = (lane >> 4) ^ (fr & 7);
  const int aOff0 = wr * 16384 + fr * 128 + c16 * 16;
  const int aOff1 = aOff0 ^ 64;
  const int bOff0 = (2 + (wc >> 1)) * 16384 + ((wc & 1) * 64 + fr) * 128 + c16 * 16;
  const int bOff1 = bOff0 ^ 64;
#define RD_A(b, mi, k32) (*(const f16x8*)(ldsB + ((k32) ? aOff1 : aOff0) + (b) * 65536 + (mi) * 2048))
#define RD_B(b, ni, k32) (*(const f16x8*)(ldsB + ((k32) ? bOff1 : bOff0) + (b) * 65536 + (ni) * 2048))

#define BAR() __builtin_amdgcn_s_barrier()
#define WLG0() asm volatile("s_waitcnt lgkmcnt(0)" ::: "memory")
#define WLG8() asm volatile("s_waitcnt lgkmcnt(8)" ::: "memory")
#define WVM4() asm volatile("s_waitcnt vmcnt(4)" ::: "memory")

  f32x4 acc[8][4];
#pragma unroll
  for (int mi = 0; mi < 8; ++mi)
#pragma unroll
    for (int ni = 0; ni < 4; ++ni) acc[mi][ni] = f32x4{0.f, 0.f, 0.f, 0.f};

  STAGE_A(0, 0); STAGE_A(0, 1); STAGE_B(0, 0); STAGE_B(0, 1);
  STAGE_B(1, 0); STAGE_B(1, 1);
  WVM4(); BAR();

#define MFMA_Q(MI0, MI1, x0, x1, x2, x3, PB)                                        \
  __builtin_amdgcn_s_setprio(1);                                                    \
  _Pragma("unroll") for (int ni = 0; ni < 4; ++ni) {                                \
    acc[MI0][ni] = __builtin_amdgcn_mfma_f32_16x16x32_f16(x0, PB[ni][0], acc[MI0][ni], 0, 0, 0); \
    acc[MI0][ni] = __builtin_amdgcn_mfma_f32_16x16x32_f16(x1, PB[ni][1], acc[MI0][ni], 0, 0, 0); \
    acc[MI1][ni] = __builtin_amdgcn_mfma_f32_16x16x32_f16(x2, PB[ni][0], acc[MI1][ni], 0, 0, 0); \
    acc[MI1][ni] = __builtin_amdgcn_mfma_f32_16x16x32_f16(x3, PB[ni][1], acc[MI1][ni], 0, 0, 0); \
  }                                                                                 \
  __builtin_amdgcn_s_setprio(0);

#define ITER8(u, msk) do {                                                          \
    const int t1 = (2 * (u) + 1) & (msk);                                           \
    const int t2 = (2 * (u) + 2) & (msk);                                           \
    const int t3 = (2 * (u) + 3) & (msk);                                           \
    f16x8 PB0[4][2];                                                                \
    _Pragma("unroll") for (int ni = 0; ni < 4; ++ni) {                              \
      PB0[ni][0] = RD_B(0, ni, 0); PB0[ni][1] = RD_B(0, ni, 1); }                   \
    {                                                                               \
      f16x8 x0 = RD_A(0, 0, 0), x1 = RD_A(0, 0, 1), x2 = RD_A(0, 1, 0), x3 = RD_A(0, 1, 1); \
      STAGE_A(t1, 0); WLG8(); BAR(); WLG0();                                        \
      MFMA_Q(0, 1, x0, x1, x2, x3, PB0) BAR();                                      \
    }                                                                               \
    {                                                                               \
      f16x8 x0 = RD_A(0, 2, 0), x1 = RD_A(0, 2, 1), x2 = RD_A(0, 3, 0), x3 = RD_A(0, 3, 1); \
      STAGE_A(t1, 1); BAR(); WLG0();                                                \
      MFMA_Q(2, 3, x0, x1, x2, x3, PB0) BAR();                                      \
    }                                                                               \
    {                                                                               \
      f16x8 x0 = RD_A(0, 4, 0), x1 = RD_A(0, 4, 1), x2 = RD_A(0, 5, 0), x3 = RD_A(0, 5, 1); \
      STAGE_B(t2, 0); BAR(); WLG0();                                                \
      MFMA_Q(4, 5, x0, x1, x2, x3, PB0) BAR();                                      \
    }                                                                               \
    {                                                                               \
      f16x8 x0 = RD_A(0, 6, 0), x1 = RD_A(0, 6, 1), x2 = RD_A(0, 7, 0), x3 = RD_A(0, 7, 1); \
      STAGE_B(t2, 1); BAR(); WLG0();                                                \
      MFMA_Q(6, 7, x0, x1, x2, x3, PB0) WVM4(); BAR();                              \
    }                                                                               \
    f16x8 PB1[4][2];                                                                \
    _Pragma("unroll") for (int ni = 0; ni < 4; ++ni) {                              \
      PB1[ni][0] = RD_B(1, ni, 0); PB1[ni][1] = RD_B(1, ni, 1); }                   \
    {                                                                               \
      f16x8 x0 = RD_A(1, 0, 0), x1 = RD_A(1, 0, 1), x2 = RD_A(1, 1, 0), x3 = RD_A(1, 1, 1); \
      STAGE_A(t2, 0); WLG8(); BAR(); WLG0();                                        \
      MFMA_Q(0, 1, x0, x1, x2, x3, PB1) BAR();                                      \
    }                                                                               \
    {                                                                               \
      f16x8 x0 = RD_A(1, 2, 0), x1 = RD_A(1, 2, 1), x2 = RD_A(1, 3, 0), x3 = RD_A(1, 3, 1); \
      STAGE_A(t2, 1); BAR(); WLG0();                                                \
      MFMA_Q(2, 3, x0, x1, x2, x3, PB1) BAR();                                      \
    }                                                                               \
    {                                                                               \
      f16x8 x0 = RD_A(1, 4, 0), x1 = RD_A(1, 4, 1), x2 = RD_A(1, 5, 0), x3 = RD_A(1, 5, 1); \
      STAGE_B(t3, 0); BAR(); WLG0();                                                \
      MFMA_Q(4, 5, x0, x1, x2, x3, PB1) BAR();                                      \
    }                                                                               \
    {                                                                               \
      f16x8 x0 = RD_A(1, 6, 0), x1 = RD_A(1, 6, 1), x2 = RD_A(1, 7, 0), x3 = RD_A(1, 7, 1); \
      STAGE_B(t3, 1); BAR(); WLG0();                                                \
      MFMA_Q(6, 7, x0, x1, x2, x3, PB1) WVM4(); BAR();                              \
    }                                                                               \
  } while (0)

  if (!rem) {
    for (int u = 0; u < 16; ++u) ITER8(u, 31);
  } else {
    for (int u = 0; u < 2; ++u) ITER8(u, 3);
  }

  const int m0 = by * 256 + wr * 128;
  const int cl = lane & 15, rq = (lane >> 4) * 4;
  if (!rem) {
    const int n0 = bxn * 256 + wc * 64;
    if (bxn < 16) {
#pragma unroll
      for (int mi = 0; mi < 8; ++mi)
#pragma unroll
        for (int r = 0; r < 4; ++r) {
          long rowoff = (long)(m0 + mi * 16 + rq + r) * 4096 + n0 + cl;
#pragma unroll
          for (int ni = 0; ni < 4; ++ni) gate[rowoff + ni * 16] = (_Float16)acc[mi][ni][r];
        }
    } else {
#pragma unroll
      for (int mi = 0; mi < 8; ++mi)
#pragma unroll
        for (int r = 0; r < 4; ++r) {
          long rowoff = (long)(m0 + mi * 16 + rq + r) * 4352 + (n0 - 4096) + cl;
#pragma unroll
          for (int ni = 0; ni < 4; ++ni) hbcf[rowoff + ni * 16] = acc[mi][ni][r];
        }
    }
  } else {
    float* rp = rparts + (long)zz * 1048576;
    const int ncol = wc * 64;
#pragma unroll
    for (int mi = 0; mi < 8; ++mi)
#pragma unroll
      for (int r = 0; r < 4; ++r) {
        long rowoff = (long)(m0 + mi * 16 + rq + r) * 256 + ncol + cl;
#pragma unroll
        for (int ni = 0; ni < 4; ++ni) rp[rowoff + ni * 16] = acc[mi][ni][r];
      }
  }
#undef STAGE_A
#undef STAGE_B
#undef RD_A
#undef RD_B
#undef ITER8
}

// == fuse2: dt_cum (16) || add_rem (1024) || transpose_wout*nw (8192) =========
__global__ __launch_bounds__(256) void fuse2(const float* __restrict__ zf,
                                             const float* __restrict__ dtb,
                                             const float* __restrict__ Alog,
                                             float* __restrict__ dt_f,
                                             float* __restrict__ cum_f,
                                             float* __restrict__ cuml,
                                             const float* __restrict__ rp,
                                             float* __restrict__ hbcf,
                                             const float* __restrict__ Wout,
                                             const float* __restrict__ nw,
                                             _Float16* __restrict__ WoutT) {
  __shared__ __attribute__((aligned(16))) char smem2[4352];
  const int bid = blockIdx.x;
  const int tid = threadIdx.x;
  if (bid < 16) {
    float (*segsum)[64] = reinterpret_cast<float (*)[64]>(smem2);
    int bc = bid;
    int h = tid & 63, seg = tid >> 6;
    int t0 = bc * 256;
    float Ah = -expf(Alog[h]);
    float bias = dtb[h];
    float s = 0.f;
    for (int j = 0; j < 64; j++) {
      int t = t0 + seg * 64 + j;
      float z = zf[(long)t * 64 + h] + bias;
      float v = (z > 20.f) ? z : log1pf(expf(z));
      dt_f[(long)t * 64 + h] = v;
      s += v * Ah;
    }
    segsum[seg][h] = s;
    __syncthreads();
    float run = 0.f;
    for (int k = 0; k < seg; k++) run += segsum[k][h];
    for (int j = 0; j < 64; j++) {
      int t = t0 + seg * 64 + j;
      run += dt_f[(long)t * 64 + h] * Ah;
      cum_f[(long)t * 64 + h] = run;
    }
    if (seg == 3) cuml[bc * 64 + h] = run;
  } else if (bid < 1040) {
    long e = ((long)(bid - 16) * 256 + tid) * 4;
    float4 s = *reinterpret_cast<const float4*>(rp + e);
#pragma unroll
    for (int z = 1; z < 8; ++z) {
      float4 v = *reinterpret_cast<const float4*>(rp + (long)z * 1048576 + e);
      s.x += v.x; s.y += v.y; s.z += v.z; s.w += v.w;
    }
    long row = e >> 8, col = e & 255;
    *reinterpret_cast<float4*>(hbcf + row * 4352 + 4096 + col) = s;
  } else {
    // transpose+cast Wout [4096,2048] -> WoutT [2048][4096], nw folded in.
    float (*tile)[33] = reinterpret_cast<float (*)[33]>(smem2);
    int i = bid - 1040;
    int c0 = (i & 63) * 32, r0 = (i >> 6) * 32;
    int tx = tid & 31, ty = tid >> 5;
#pragma unroll
    for (int j = 0; j < 4; j++)
      tile[ty + j * 8][tx] = Wout[(long)(r0 + ty + j * 8) * 2048 + c0 + tx];
    __syncthreads();
    float nwr = nw[r0 + tx];
#pragma unroll
    for (int j = 0; j < 4; j++) {
      int c = c0 + ty + j * 8, r = r0 + tx;
      WoutT[(long)c * 4096 + r] = (_Float16)(tile[tx][ty + j * 8] * nwr);
    }
  }
}

// ======= convx: conv(K=4)+SiLU fused with transposes: x->xT16, B->BT16 =======
__global__ __launch_bounds__(256) void convx(const float* __restrict__ hbcf,
                                             const float* __restrict__ convw,
                                             const float* __restrict__ convb,
                                             _Float16* __restrict__ x16,
                                             _Float16* __restrict__ B16,
                                             _Float16* __restrict__ C16,
                                             unsigned short* __restrict__ xT16,
                                             unsigned short* __restrict__ BT16) {
  __shared__ unsigned short tile[64][66];
  const int bx = blockIdx.x, t0 = blockIdx.y * 64;
  const int tid = threadIdx.x;
  const int tq = tid & 63, tg = tid >> 6;
  const int q0 = (bx < 64) ? bx * 64 : 4096 + (bx - 64) * 64;
  const int q = q0 + tq;
  const int ts = t0 + tg * 16;
  const int bstart = ts & ~2047;
  const float* colq = hbcf + q;
  float4 wq = *reinterpret_cast<const float4*>(convw + q * 4);
  float bconv = convb[q];
  float v3 = (ts - 3 >= bstart) ? colq[(long)(ts - 3) * 4352] : 0.f;
  float v2 = (ts - 2 >= bstart) ? colq[(long)(ts - 2) * 4352] : 0.f;
  float v1 = (ts - 1 >= bstart) ? colq[(long)(ts - 1) * 4352] : 0.f;
  if (bx < 64) {
#pragma unroll
    for (int j = 0; j < 16; ++j) {
      int t = ts + j;
      float v0 = colq[(long)t * 4352];
      float a = bconv + v3 * wq.x + v2 * wq.y + v1 * wq.z + v0 * wq.w;
      unsigned short o = f2h(siluf(a));
      ((unsigned short*)x16)[(long)t * 4096 + q] = o;
      tile[tg * 16 + j][tq] = o;
      v3 = v2; v2 = v1; v1 = v0;
    }
    __syncthreads();
    int tx = tid & 15, ty = tid >> 4;
#pragma unroll
    for (int i = 0; i < 4; ++i) {
      int c = ty + i * 16;
      ushort4 v;
      v.x = tile[4 * tx + 0][c]; v.y = tile[4 * tx + 1][c];
      v.z = tile[4 * tx + 2][c]; v.w = tile[4 * tx + 3][c];
      *(ushort4*)&xT16[(long)(q0 + c) * 4096 + t0 + 4 * tx] = v;
    }
  } else if (bx < 66) {
    // B cols: row-major B16 + transposed BT16[n][t]
    const int n0 = q0 - 4096;
#pragma unroll
    for (int j = 0; j < 16; ++j) {
      int t = ts + j;
      float v0 = colq[(long)t * 4352];
      float a = bconv + v3 * wq.x + v2 * wq.y + v1 * wq.z + v0 * wq.w;
      unsigned short o = f2h(siluf(a));
      ((unsigned short*)B16)[(long)t * 128 + (q - 4096)] = o;
      tile[tg * 16 + j][tq] = o;
      v3 = v2; v2 = v1; v1 = v0;
    }
    __syncthreads();
    int tx = tid & 15, ty = tid >> 4;
#pragma unroll
    for (int i = 0; i < 4; ++i) {
      int c = ty + i * 16;
      ushort4 v;
      v.x = tile[4 * tx + 0][c]; v.y = tile[4 * tx + 1][c];
      v.z = tile[4 * tx + 2][c]; v.w = tile[4 * tx + 3][c];
      *(ushort4*)&BT16[(long)(n0 + c) * 4096 + t0 + 4 * tx] = v;
    }
  } else {
#pragma unroll
    for (int j = 0; j < 16; ++j) {
      int t = ts + j;
      float v0 = colq[(long)t * 4352];
      float a = bconv + v3 * wq.x + v2 * wq.y + v1 * wq.z + v0 * wq.w;
      _Float16 o = (_Float16)siluf(a);
      C16[(long)t * 128 + (q - 4224)] = o;
      v3 = v2; v2 = v1; v1 = v0;
    }
  }
}

// ========= fuse3: states_mfma (1024) || CBTt gemm (64) || ssq zero (4) =======
__global__ __launch_bounds__(256) void fuse3(const unsigned short* __restrict__ xT16,
                                             const unsigned short* __restrict__ BT16,
                                             const _Float16* __restrict__ B16,
                                             const _Float16* __restrict__ C16,
                                             const float* __restrict__ dt_f,
                                             const float* __restrict__ cum_f,
                                             const float* __restrict__ cuml,
                                             float* __restrict__ states,
                                             float* __restrict__ CBT,
                                             float* __restrict__ ssq) {
  __shared__ __attribute__((aligned(16))) char smem3[16384];
  const int bid = blockIdx.x;
  const int tid = threadIdx.x;
  const int wv = tid >> 6, lane = tid & 63;
  const int mr = lane & 15, koff = (lane >> 4) * 8;
  if (bid < 1024) {
    float* w_s = (float*)smem3;
    unsigned short* Aw = (unsigned short*)(smem3 + 1024);
    int h = bid & 63, bc = bid >> 6;
    int t0 = bc * 256;
    {
      int t = t0 + tid;
      w_s[tid] = expf(cuml[bc * 64 + h] - cum_f[(long)t * 64 + h]) * dt_f[(long)t * 64 + h];
    }
    __syncthreads();
    f32x4 acc[4][2];
#pragma unroll
    for (int mi = 0; mi < 4; mi++)
#pragma unroll
      for (int nj = 0; nj < 2; nj++) acc[mi][nj] = f32x4{0.f, 0.f, 0.f, 0.f};
    const unsigned short* btb = BT16 + t0 + koff;
    for (int kt = 0; kt < 8; kt++) {
      {
        int p = tid >> 2, tq2 = tid & 3;
        const unsigned short* g = &xT16[((long)(h * 64 + p)) * 4096 + t0 + kt * 32 + tq2 * 8];
        ushort4 u0 = *(const ushort4*)g, u1 = *(const ushort4*)(g + 4);
        const float* wp = &w_s[kt * 32 + tq2 * 8];
        ushort4 o0, o1;
        o0.x = f2h(h2f(u0.x) * wp[0]); o0.y = f2h(h2f(u0.y) * wp[1]);
        o0.z = f2h(h2f(u0.z) * wp[2]); o0.w = f2h(h2f(u0.w) * wp[3]);
        o1.x = f2h(h2f(u1.x) * wp[4]); o1.y = f2h(h2f(u1.y) * wp[5]);
        o1.z = f2h(h2f(u1.z) * wp[6]); o1.w = f2h(h2f(u1.w) * wp[7]);
        *(ushort4*)&Aw[p * 40 + tq2 * 8] = o0;
        *(ushort4*)&Aw[p * 40 + tq2 * 8 + 4] = o1;
      }
      __syncthreads();
      f16x8 af[4], bf[2];
#pragma unroll
      for (int mi = 0; mi < 4; mi++)
        af[mi] = *(const f16x8*)&Aw[(mi * 16 + mr) * 40 + koff];
#pragma unroll
      for (int nj = 0; nj < 2; nj++)
        bf[nj] = *(const f16x8*)(btb + (long)((wv * 2 + nj) * 16 + mr) * 4096 + kt * 32);
#pragma unroll
      for (int mi = 0; mi < 4; mi++)
#pragma unroll
        for (int nj = 0; nj < 2; nj++)
          acc[mi][nj] = __builtin_amdgcn_mfma_f32_16x16x32_f16(af[mi], bf[nj],
                                                               acc[mi][nj], 0, 0, 0);
      __syncthreads();
    }
    int cl = lane & 15, rq = (lane >> 4) * 4;
    long base = ((long)(bc * 64 + h)) * 8192;
#pragma unroll
    for (int mi = 0; mi < 4; mi++)
#pragma unroll
      for (int r = 0; r < 4; r++) {
        int p = mi * 16 + rq + r;
#pragma unroll
        for (int nj = 0; nj < 2; nj++) {
          int n = (wv * 2 + nj) * 16 + cl;
          states[base + p * 128 + n] = acc[mi][nj][r];
        }
      }
  } else if (bid < 1088) {
    _Float16* As = (_Float16*)smem3;
    _Float16* Bs = (_Float16*)(smem3 + 8192);
    int i = bid - 1024;
    int bx = i & 1, by = (i >> 1) & 1, bz = i >> 2;
    // TRANSPOSED production: A = B16 rows (j), B = C16 rows (i)
    const _Float16* Ab = B16 + (long)bz * 32768 + (long)by * 128 * 128;
    const _Float16* Bb = C16 + (long)bz * 32768 + (long)bx * 128 * 128;
    const int c0 = wv * 128 + lane;
    const int c1 = c0 + 64;
    const long ra0 = (long)(c0 >> 2) * 128 + (c0 & 3) * 8;
    const long ra1 = (long)(c1 >> 2) * 128 + (c1 & 3) * 8;
    f32x4 acc[4][4];
#pragma unroll
    for (int mi = 0; mi < 4; mi++)
#pragma unroll
      for (int ni = 0; ni < 4; ni++) acc[mi][ni] = f32x4{0.f, 0.f, 0.f, 0.f};
    const int mrow = (wv & 1) * 64 + (lane & 15);
    const int nrow = (wv >> 1) * 64 + (lane & 15);
    for (int k0 = 0; k0 < 128; k0 += 32) {
      GLD16(Ab + ra0 + k0, (char*)As + c0 * 16);
      GLD16(Ab + ra1 + k0, (char*)As + c1 * 16);
      GLD16(Bb + ra0 + k0, (char*)Bs + c0 * 16);
      GLD16(Bb + ra1 + k0, (char*)Bs + c1 * 16);
      __syncthreads();
      f16x8 af[4], bfr[4];
#pragma unroll
      for (int mi = 0; mi < 4; mi++)
        af[mi] = *(const f16x8*)(As + (mrow + mi * 16) * 32 + koff);
#pragma unroll
      for (int ni = 0; ni < 4; ni++)
        bfr[ni] = *(const f16x8*)(Bs + (nrow + ni * 16) * 32 + koff);
#pragma unroll
      for (int mi = 0; mi < 4; mi++)
#pragma unroll
        for (int ni = 0; ni < 4; ni++)
          acc[mi][ni] = __builtin_amdgcn_mfma_f32_16x16x32_f16(af[mi], bfr[ni],
                                                               acc[mi][ni], 0, 0, 0);
      __syncthreads();
    }
    const int m0 = by * 128 + (wv & 1) * 64;
    const int n0 = bx * 128 + (wv >> 1) * 64;
    const int cl = lane & 15, rq = (lane >> 4) * 4;
    const long zc = (long)bz * 65536;
#pragma unroll
    for (int mi = 0; mi < 4; mi++)
#pragma unroll
      for (int r = 0; r < 4; r++) {
        long rowoff = zc + (long)(m0 + mi * 16 + rq + r) * 256 + n0 + cl;
#pragma unroll
        for (int ni = 0; ni < 4; ni++) CBT[rowoff + ni * 16] = acc[mi][ni][r];
      }
  } else {
    // zero ssq[4096]
    int i = (bid - 1088) * 1024 + tid * 4;
    *reinterpret_cast<float4*>(&ssq[i]) = make_float4(0.f, 0.f, 0.f, 0.f);
  }
}

// ------------- inter-chunk recurrence (1024 blocks: 128 bh x 8 j-slices) -----
__global__ __launch_bounds__(256) void recur_kernel(float* __restrict__ states,
                                                    const float* __restrict__ cuml) {
  int g = blockIdx.x;
  int bh = g >> 3, js = g & 7;
  int b = bh >> 6, h = bh & 63;
  int tid = threadIdx.x;
  float4 prev = make_float4(0.f, 0.f, 0.f, 0.f);
  for (int c = 0; c < 8; c++) {
    int bc = b * 8 + c;
    float cd = expf(cuml[bc * 64 + h]);
    long o = (long)(bc * 64 + h) * 8192 + js * 1024 + tid * 4;
    float4 st = *reinterpret_cast<const float4*>(&states[o]);
    *reinterpret_cast<float4*>(&states[o]) = prev;
    prev.x = fmaf(cd, prev.x, st.x);
    prev.y = fmaf(cd, prev.y, st.y);
    prev.z = fmaf(cd, prev.z, st.z);
    prev.w = fmaf(cd, prev.w, st.w);
  }
}

// ---------------- fused Y = Ydiag + Yoff + D*x, then *SiLU(gate) -> hid fp16
__global__ __launch_bounds__(256) void yfused(const unsigned short* __restrict__ xT16,
                                              const unsigned short* __restrict__ x16,
                                              const unsigned short* __restrict__ C16,
                                              const unsigned short* __restrict__ gate,
                                              const float* __restrict__ CBTt,
                                              const float* __restrict__ states,
                                              const float* __restrict__ dt_f,
                                              const float* __restrict__ cum_f,
                                              const float* __restrict__ Dp,
                                              unsigned short* __restrict__ hid,
                                              float* __restrict__ ssq) {
  int h = blockIdx.x, bc = blockIdx.y;
  int t0 = bc * 256, tid = threadIdx.x;
  __shared__ unsigned short Sb[256 * 40];   // 20480: per-wave-owned S / Afac
  __shared__ unsigned short Xb[64 * 264];   // 33792: xT tile (coalesced staging)
  __shared__ unsigned short PS[64 * 136];   // 17408: states fp16
  __shared__ float c2_s[256], dt_s[256];    // 2048  (total 73728)
  int i = tid;
  c2_s[i] = cum_f[(long)(t0 + i) * 64 + h] * 1.44269504f;
  dt_s[i] = dt_f[(long)(t0 + i) * 64 + h];
  {  // stage xT tile
    int p = tid >> 2, tq = tid & 3;
    const unsigned short* g = &xT16[((long)(h * 64 + p)) * 4096 + t0 + tq * 64];
    unsigned short* l = &Xb[p * 264 + tq * 64];
#pragma unroll
    for (int c = 0; c < 8; c++)
      *(uint4*)(l + c * 8) = *(const uint4*)(g + c * 8);
  }
  {  // stage PS16 (states -> fp16)
    int p = tid >> 2, nq = tid & 3;
    const float* g = &states[((long)(bc * 64 + h)) * 8192 + p * 128 + nq * 32];
    unsigned short* l = &PS[p * 136 + nq * 32];
#pragma unroll
    for (int c = 0; c < 8; c++) {
      float4 v = *(const float4*)(g + c * 4);
      ushort4 u;
      u.x = f2h(v.x); u.y = f2h(v.y); u.z = f2h(v.z); u.w = f2h(v.w);
      *(ushort4*)(l + c * 4) = u;
    }
  }
  __syncthreads();  // the ONLY barrier
  float c2_i = c2_s[i];
  const float* cbcol = CBTt + (long)bc * 65536 + i;  // lane-coalesced column
  int wv = tid >> 6, lane = tid & 63;
  int mr = lane & 15, koff = (lane >> 4) * 8;
  f32x4 acc[4][4];
#pragma unroll
  for (int mi = 0; mi < 4; mi++)
#pragma unroll
    for (int ni = 0; ni < 4; ni++) acc[mi][ni] = f32x4{0.f, 0.f, 0.f, 0.f};
  // ---------------- ydiag: per-wave causal range, barrier-free
  const int ktmax = 2 * wv + 2;
  for (int kt = 0; kt < ktmax; kt++) {
    int k0 = kt * 32;
#pragma unroll
    for (int c = 0; c < 8; c++) {
      int jb = k0 + c * 4;
      float cb0 = cbcol[(long)(jb + 0) * 256];
      float cb1 = cbcol[(long)(jb + 1) * 256];
      float cb2 = cbcol[(long)(jb + 2) * 256];
      float cb3 = cbcol[(long)(jb + 3) * 256];
      ushort4 o;
      o.x = f2h((jb + 0 <= i) ? cb0 * exp2f(c2_i - c2_s[jb + 0]) * dt_s[jb + 0] : 0.f);
      o.y = f2h((jb + 1 <= i) ? cb1 * exp2f(c2_i - c2_s[jb + 1]) * dt_s[jb + 1] : 0.f);
      o.z = f2h((jb + 2 <= i) ? cb2 * exp2f(c2_i - c2_s[jb + 2]) * dt_s[jb + 2] : 0.f);
      o.w = f2h((jb + 3 <= i) ? cb3 * exp2f(c2_i - c2_s[jb + 3]) * dt_s[jb + 3] : 0.f);
      *(ushort4*)&Sb[i * 40 + c * 4] = o;
    }
    f16x8 af[4], bf[4];
#pragma unroll
    for (int mi = 0; mi < 4; mi++)
      af[mi] = *(const f16x8*)&Sb[(64 * wv + mi * 16 + mr) * 40 + koff];
#pragma unroll
    for (int ni = 0; ni < 4; ni++)
      bf[ni] = *(const f16x8*)&Xb[(ni * 16 + mr) * 264 + k0 + koff];
#pragma unroll
    for (int mi = 0; mi < 4; mi++)
#pragma unroll
      for (int ni = 0; ni < 4; ni++)
        acc[mi][ni] = __builtin_amdgcn_mfma_f32_16x16x32_f16(af[mi], bf[ni],
                                                             acc[mi][ni], 0, 0, 0);
  }
  // ---------------- yoff: barrier-free (PS staged up-front)
  float fac_i = exp2f(c2_i);
  for (int kn = 0; kn < 4; kn++) {
    {  // form Afac row i
      const unsigned short* g = &C16[((long)(t0 + i)) * 128 + kn * 32];
#pragma unroll
      for (int c = 0; c < 8; c++) {
        ushort4 u = *(const ushort4*)(g + c * 4);
        ushort4 o;
        o.x = f2h(h2f(u.x) * fac_i); o.y = f2h(h2f(u.y) * fac_i);
        o.z = f2h(h2f(u.z) * fac_i); o.w = f2h(h2f(u.w) * fac_i);
        *(ushort4*)&Sb[i * 40 + c * 4] = o;
      }
    }
    f16x8 af[4], bf[4];
#pragma unroll
    for (int mi = 0; mi < 4; mi++)
      af[mi] = *(const f16x8*)&Sb[(64 * wv + mi * 16 + mr) * 40 + koff];
#pragma unroll
    for (int ni = 0; ni < 4; ni++)
      bf[ni] = *(const f16x8*)&PS[(ni * 16 + mr) * 136 + kn * 32 + koff];
#pragma unroll
    for (int mi = 0; mi < 4; mi++)
#pragma unroll
      for (int ni = 0; ni < 4; ni++)
        acc[mi][ni] = __builtin_amdgcn_mfma_f32_16x16x32_f16(af[mi], bf[ni],
                                                             acc[mi][ni], 0, 0, 0);
  }
  // epilogue: y = acc + D*x; h = y*silu(gate); store fp16 + per-row ssq
  float Dh = Dp[h];
  int cl = lane & 15, rq = (lane >> 4) * 4;
#pragma unroll
  for (int mi = 0; mi < 4; mi++)
#pragma unroll
    for (int r = 0; r < 4; r++) {
      long row = t0 + 64 * wv + mi * 16 + rq + r;
      const unsigned short* xr = &x16[row * 4096 + h * 64];
      const unsigned short* gr = &gate[row * 4096 + h * 64];
      unsigned short* hw = &hid[row * 4096 + h * 64];
      float ssp = 0.f;
#pragma unroll
      for (int ni = 0; ni < 4; ni++) {
        int p = ni * 16 + cl;
        float yv = acc[mi][ni][r] + Dh * h2f(xr[p]);
        float hv = yv * siluf(h2f(gr[p]));
        hw[p] = f2h(hv);
        ssp += hv * hv;
      }
#pragma unroll
      for (int o = 8; o > 0; o >>= 1) ssp += __shfl_down(ssp, o, 16);
      if (cl == 0) atomicAdd(&ssq[row], ssp);
    }
}

// ====== out_proj GEMM: 256^2 tile, split-K (z=4, K=1024/slice), 8-phase ======
// grid 512 = 16 by x 8 bx x 4 z -> 2 blocks/CU co-resident (TLP restored).
__global__ __launch_bounds__(512, 2) void gemm_out8(const _Float16* __restrict__ A,
                                                    const _Float16* __restrict__ Bt,
                                                    float* __restrict__ Cp0,
                                                    float* __restrict__ Cp1,
                                                    float* __restrict__ Cp2,
                                                    float* __restrict__ Cp3) {
  __shared__ __attribute__((aligned(128))) char ldsB[131072];
  const int tid = threadIdx.x;
  const int lane = tid & 63;
  const int wv = tid >> 6;
  const int wr = wv >> 2, wc = wv & 3;
  const int wg = blockIdx.x;
  const int xcd = wg & 7, j = wg >> 3;   // j in [0,64)
  const int z = j >> 4, t = j & 15;
  const int by = (xcd >> 1) * 4 + (t >> 2);
  const int bx = (xcd & 1) * 4 + (t & 3);

  const int srow = tid >> 3;
  const int scolg = (tid & 7) ^ (srow & 7);
  const _Float16* Ab = A + (long)by * 256 * 4096 + (long)z * 1024 +
                       (long)srow * 4096 + scolg * 8;
  const _Float16* Bb = Bt + (long)bx * 256 * 4096 + (long)z * 1024 +
                       (long)srow * 4096 + scolg * 8;
  const int ldst = tid << 4;

#define STAGE_A(tau, h) do {                                              \
    const _Float16* g_ = Ab + (long)(h) * 524288 + (tau) * 64;            \
    char* l_ = ldsB + ((((tau) & 1) << 2) + (h)) * 16384 + ldst;          \
    GLD16(g_, l_); GLD16(g_ + 262144, l_ + 8192); } while (0)
#define STAGE_B(tau, h) do {                                              \
    const _Float16* g_ = Bb + (long)(h) * 524288 + (tau) * 64;            \
    char* l_ = ldsB + ((((tau) & 1) << 2) + 2 + (h)) * 16384 + ldst;      \
    GLD16(g_, l_); GLD16(g_ + 262144, l_ + 8192); } while (0)

  const int fr = lane & 15;
  const int c16 = (lane >> 4) ^ (fr & 7);
  const int aOff0 = wr * 16384 + fr * 128 + c16 * 16;
  const int aOff1 = aOff0 ^ 64;
  const int bOff0 = (2 + (wc >> 1)) * 16384 + ((wc & 1) * 64 + fr) * 128 + c16 * 16;
  const int bOff1 = bOff0 ^ 64;
#define RD_A(b, mi, k32) (*(const f16x8*)(ldsB + ((k32) ? aOff1 : aOff0) + (b) * 65536 + (mi) * 2048))
#define RD_B(b, ni, k32) (*(const f16x8*)(ldsB + ((k32) ? bOff1 : bOff0) + (b) * 65536 + (ni) * 2048))

#define BAR() __builtin_amdgcn_s_barrier()
#define WLG0() asm volatile("s_waitcnt lgkmcnt(0)" ::: "memory")
#define WLG8() asm volatile("s_waitcnt lgkmcnt(8)" ::: "memory")
#define WVM4() asm volatile("s_waitcnt vmcnt(4)" ::: "memory")

  f32x4 acc[8][4];
#pragma unroll
  for (int mi = 0; mi < 8; ++mi)
#pragma unroll
    for (int ni = 0; ni < 4; ++ni) acc[mi][ni] = f32x4{0.f, 0.f, 0.f, 0.f};

  STAGE_A(0, 0); STAGE_A(0, 1); STAGE_B(0, 0); STAGE_B(0, 1);
  STAGE_B(1, 0); STAGE_B(1, 1);
  WVM4(); BAR();

#define MFMA_Q(MI0, MI1, x0, x1, x2, x3, PB)                                        \
  __builtin_amdgcn_s_setprio(1);                                                    \
  _Pragma("unroll") for (int ni = 0; ni < 4; ++ni) {                                \
    acc[MI0][ni] = __builtin_amdgcn_mfma_f32_16x16x32_f16(x0, PB[ni][0], acc[MI0][ni], 0, 0, 0); \
    acc[MI0][ni] = __builtin_amdgcn_mfma_f32_16x16x32_f16(x1, PB[ni][1], acc[MI0][ni], 0, 0, 0); \
    acc[MI1][ni] = __builtin_amdgcn_mfma_f32_16x16x32_f16(x2, PB[ni][0], acc[MI1][ni], 0, 0, 0); \
    acc[MI1][ni] = __builtin_amdgcn_mfma_f32_16x16x32_f16(x3, PB[ni][1], acc[MI1][ni], 0, 0, 0); \
  }                                                                                 \
  __builtin_amdgcn_s_setprio(0);

  for (int u = 0; u < 8; ++u) {
    const int t1 = (2 * u + 1) & 15;
    const int t2 = (2 * u + 2) & 15;
    const int t3 = (2 * u + 3) & 15;
    f16x8 PB0[4][2];
#pragma unroll
    for (int ni = 0; ni < 4; ++ni) { PB0[ni][0] = RD_B(0, ni, 0); PB0[ni][1] = RD_B(0, ni, 1); }
    {
      f16x8 x0 = RD_A(0, 0, 0), x1 = RD_A(0, 0, 1), x2 = RD_A(0, 1, 0), x3 = RD_A(0, 1, 1);
      STAGE_A(t1, 0); WLG8(); BAR(); WLG0();
      MFMA_Q(0, 1, x0, x1, x2, x3, PB0) BAR();
    }
    {
      f16x8 x0 = RD_A(0, 2, 0), x1 = RD_A(0, 2, 1), x2 = RD_A(0, 3, 0), x3 = RD_A(0, 3, 1);
      STAGE_A(t1, 1); BAR(); WLG0();
      MFMA_Q(2, 3, x0, x1, x2, x3, PB0) BAR();
    }
    {
      f16x8 x0 = RD_A(0, 4, 0), x1 = RD_A(0, 4, 1), x2 = RD_A(0, 5, 0), x3 = RD_A(0, 5, 1);
      STAGE_B(t2, 0); BAR(); WLG0();
      MFMA_Q(4, 5, x0, x1, x2, x3, PB0) BAR();
    }
    {
      f16x8 x0 = RD_A(0, 6, 0), x1 = RD_A(0, 6, 1), x2 = RD_A(0, 7, 0), x3 = RD_A(0, 7, 1);
      STAGE_B(t2, 1); BAR(); WLG0();
      MFMA_Q(6, 7, x0, x1, x2, x3, PB0) WVM4(); BAR();
    }
    f16x8 PB1[4][2];
#pragma unroll
    for (int ni = 0; ni < 4; ++ni) { PB1[ni][0] = RD_B(1, ni, 0); PB1[ni][1] = RD_B(1, ni, 1); }
    {
      f16x8 x0 = RD_A(1, 0, 0), x1 = RD_A(1, 0, 1), x2 = RD_A(1, 1, 0), x3 = RD_A(1, 1, 1);
      STAGE_A(t2, 0); WLG8(); BAR(); WLG0();
      MFMA_Q(0, 1, x0, x1, x2, x3, PB1) BAR();
    }
    {
      f16x8 x0 = RD_A(1, 2, 0), x1 = RD_A(1, 2, 1), x2 = RD_A(1, 3, 0), x3 = RD_A(1, 3, 1);
      STAGE_A(t2, 1); BAR(); WLG0();
      MFMA_Q(2, 3, x0, x1, x2, x3, PB1) BAR();
    }
    {
      f16x8 x0 = RD_A(1, 4, 0), x1 = RD_A(1, 4, 1), x2 = RD_A(1, 5, 0), x3 = RD_A(1, 5, 1);
      STAGE_B(t3, 0); BAR(); WLG0();
      MFMA_Q(4, 5, x0, x1, x2, x3, PB1) BAR();
    }
    {
      f16x8 x0 = RD_A(1, 6, 0), x1 = RD_A(1, 6, 1), x2 = RD_A(1, 7, 0), x3 = RD_A(1, 7, 1);
      STAGE_B(t3, 1); BAR(); WLG0();
      MFMA_Q(6, 7, x0, x1, x2, x3, PB1) WVM4(); BAR();
    }
  }
  const int m0 = by * 256 + wr * 128;
  const int n0 = bx * 256 + wc * 64;
  const int cl = lane & 15, rq = (lane >> 4) * 4;
  float* Cb = (z == 0) ? Cp0 : (z == 1) ? Cp1 : (z == 2) ? Cp2 : Cp3;
#pragma unroll
  for (int mi = 0; mi < 8; ++mi)
#pragma unroll
    for (int r = 0; r < 4; ++r) {
      long rowoff = (long)(m0 + mi * 16 + rq + r) * 2048 + n0 + cl;
#pragma unroll
      for (int ni = 0; ni < 4; ++ni) Cb[rowoff + ni * 16] = acc[mi][ni][r];
    }
#undef STAGE_A
#undef STAGE_B
#undef RD_A
#undef RD_B
#undef BAR
#undef WLG0
#undef WLG8
#undef WVM4
#undef MFMA_Q
}

// ------------- sum the four split-K partials, apply RMS row-scale -----------
__global__ __launch_bounds__(256) void add_out(const float* __restrict__ p0,
                                               const float* __restrict__ p1,
                                               const float* __restrict__ p2,
                                               const float* __restrict__ p3,
                                               const float* __restrict__ ssq,
                                               float* __restrict__ o) {
  long i = ((long)blockIdx.x * 256 + threadIdx.x) * 4;
  float sc = rsqrtf(ssq[i >> 11] * (1.f / 4096.f) + 1e-5f);
  float4 a = *reinterpret_cast<const float4*>(p0 + i);
  float4 b = *reinterpret_cast<const float4*>(p1 + i);
  float4 c = *reinterpret_cast<const float4*>(p2 + i);
  float4 d = *reinterpret_cast<const float4*>(p3 + i);
  float4 r;
  r.x = ((a.x + b.x) + (c.x + d.x)) * sc;
  r.y = ((a.y + b.y) + (c.y + d.y)) * sc;
  r.z = ((a.z + b.z) + (c.z + d.z)) * sc;
  r.w = ((a.w + b.w) + (c.w + d.w)) * sc;
  *reinterpret_cast<float4*>(o + i) = r;
}

// =============================================================== launch
extern "C" void kernel_launch(void* const* d_in, const int* in_sizes, int n_in,
                              void* d_out, int out_size, void* d_ws, size_t ws_size,
                              hipStream_t stream) {
  (void)in_sizes; (void)n_in; (void)out_size; (void)ws_size;
  const float* hs    = (const float*)d_in[0];
  const float* Win   = (const float*)d_in[1];
  const float* convw = (const float*)d_in[2];
  const float* convb = (const float*)d_in[3];
  const float* dtb   = (const float*)d_in[4];
  const float* Alog  = (const float*)d_in[5];
  const float* Dp    = (const float*)d_in[6];
  const float* nw    = (const float*)d_in[7];
  const float* Wout  = (const float*)d_in[8];
  float* out = (float*)d_out;

  char* base = (char*)d_ws;
  size_t off = 0;
  auto take = [&](size_t n) { char* r = base + off; off += (n + 255) & ~(size_t)255; return r; };
  float*    hbcf  = (float*)take(4096UL * 4352 * 4);    // gemm_in -> conv; then hid (fp16)
  _Float16* gateh = (_Float16*)take(4096UL * 4096 * 2); // gemm_in -> yfused; then oparts1
  _Float16* Ah    = (_Float16*)take(4096UL * 2048 * 2); // cast -> gemm_in; then WoutT
  _Float16* WtH   = (_Float16*)take(8448UL * 2048 * 2); // trans -> gemm_in; x16; then oparts3
  _Float16* xT16  = (_Float16*)take(4096UL * 4096 * 2); // convx -> states/yfused; then oparts2
  _Float16* B16   = (_Float16*)take(4096UL * 128 * 2);
  _Float16* BT16  = (_Float16*)take(128UL * 4096 * 2);  // convx -> fuse3 (transposed B)
  _Float16* C16   = (_Float16*)take(4096UL * 128 * 2);
  float*    zf    = (float*)take(4096UL * 64 * 4);
  float*    dt_f  = (float*)take(4096UL * 64 * 4);
  float*    cum_f = (float*)take(4096UL * 64 * 4);
  float*    cuml  = (float*)take(16UL * 64 * 4);
  float*    ssq   = (float*)take(4096UL * 4);
  float*    CBT   = (float*)take(16UL * 256 * 256 * 4);  // TRANSPOSED: [bc][j][i]
  float*    states= (float*)take(1024UL * 8192 * 4);    // rparts; states -> prevs; then oparts0
  // overlays:
  float*    rparts = states;              // live gemm_in8..fuse2 (8 x 4MB = 32MB)
  _Float16* WoutT  = Ah;                  // written by fuse2 (after gemm_in8)
  _Float16* x16    = WtH;                 // written by convx (after gemm_in8)
  unsigned short* hid = (unsigned short*)hbcf;  // live yfused..gemm_out8 (33.5MB in 71MB)
  float*    oparts0 = states;             // dead after yfused (33.55MB)
  float*    oparts1 = (float*)gateh;      // dead after yfused (33.55MB)
  float*    oparts2 = (float*)xT16;       // dead after yfused (33.55MB)
  float*    oparts3 = (float*)WtH;        // dead after yfused (34.6MB)

  // 1. prep: dtz || cast || transpose_win (one launch)
  prep<<<26112, 256, 0, stream>>>(hs, Win, Ah, WtH, zf);
  // 2. fp16 in_proj GEMM (256^2 8-phase; square per-XCD regions + remainder)
  gemm_in8<<<dim3(640), 512, 0, stream>>>(Ah, WtH, gateh, hbcf, rparts);
  // 3. fuse2: dt_cum || add_rem || transpose_wout (nw folded) (one launch)
  fuse2<<<9232, 256, 0, stream>>>(zf, dtb, Alog, dt_f, cum_f, cuml,
                                  rparts, hbcf, Wout, nw, WoutT);
  // 4. convx: rolling-tap conv+SiLU fused with x->xT and B->BT transposes
  convx<<<dim3(68, 64), 256, 0, stream>>>(hbcf, convw, convb, x16, B16, C16,
                                          (unsigned short*)xT16,
                                          (unsigned short*)BT16);
  // 5. fuse3: states_mfma (B-frags from BT16) || CBTt gemm || ssq zero
  fuse3<<<1092, 256, 0, stream>>>((const unsigned short*)xT16,
                                  (const unsigned short*)BT16, B16, C16,
                                  dt_f, cum_f, cuml, states, CBT, ssq);
  // 6. inter-chunk recurrence (1024 blocks)
  recur_kernel<<<1024, 256, 0, stream>>>(states, cuml);
  // 7. yfused: Ydiag+Yoff+D*x, *SiLU(gate) -> hid fp16 (un-normalized) + ssq
  yfused<<<dim3(64, 16), 256, 0, stream>>>((const unsigned short*)xT16,
                                           (const unsigned short*)x16,
                                           (const unsigned short*)C16,
                                           (const unsigned short*)gateh,
                                           CBT, states, dt_f, cum_f, Dp,
                                           hid, ssq);
  // 8. out_proj GEMM (256^2 8-phase, split-K z=4, 2 blocks/CU)
  gemm_out8<<<dim3(512), 512, 0, stream>>>((const _Float16*)hid, WoutT,
                                           oparts0, oparts1, oparts2, oparts3);
  // 9. sum 4 partials, apply RMS row-scale -> d_out fp32
  add_out<<<8192, 256, 0, stream>>>(oparts0, oparts1, oparts2, oparts3, ssq, out);
}

// Round 13
// 695.457 us; speedup vs baseline: 1.0249x; 1.0249x over previous
//
#include <hip/hip_runtime.h>
#include <hip/hip_bf16.h>

// Mamba2 mixer forward, MI355X. B=2, L=2048, D_MODEL=2048, H=64, P=64, N=128,
// G=1, K=4, CHUNK=256. T = 4096 tokens, 16 chunks.
// Round 13: revert round-12's split-K z=4 (its +134MB partial traffic cost
// ~21us > TLP gain); out_proj back to round-11 form (z=2, RMS folded into
// add_out). Keep round-12's fast silu (3-inst sigmoid). Everything else = r11.

typedef __attribute__((ext_vector_type(8))) _Float16 f16x8;
typedef __attribute__((ext_vector_type(4))) float f32x4;

#define GLD16(gp, lp) __builtin_amdgcn_global_load_lds( \
    (__attribute__((address_space(1))) void*)(gp),      \
    (__attribute__((address_space(3))) void*)(lp), 16, 0, 0)

__device__ __forceinline__ unsigned short f2h(float v) {
  _Float16 h = (_Float16)v;
  return *reinterpret_cast<unsigned short*>(&h);
}
__device__ __forceinline__ float h2f(unsigned short u) {
  _Float16 h = *reinterpret_cast<_Float16*>(&u);
  return (float)h;
}
// fast silu: x * sigmoid(x); sigmoid via single v_exp + v_rcp (~1ulp approx).
__device__ __forceinline__ float siluf(float x) {
  return x * __builtin_amdgcn_rcpf(1.f + exp2f(x * -1.44269504f));
}

// ===================== prep: dtz (1024) || cast_f16 (8192) || twin (16896) ===
__global__ __launch_bounds__(256) void prep(const float* __restrict__ hs,
                                            const float* __restrict__ Win,
                                            _Float16* __restrict__ Ah,
                                            _Float16* __restrict__ WtH,
                                            float* __restrict__ zf) {
  __shared__ __attribute__((aligned(16))) char smemP[32768];
  const int bid = blockIdx.x;
  const int tid = threadIdx.x;
  if (bid < 1024) {
    // ---- dtz: fp32 dt pre-activation (exact slice)
    float (*Xs)[2048] = reinterpret_cast<float (*)[2048]>(smemP);
    int t0 = bid * 4;
#pragma unroll
    for (int i = 0; i < 8; i++) {
      int e = tid * 4 + i * 1024;
      int tok = e >> 11, k = e & 2047;
      *reinterpret_cast<float4*>(&Xs[tok][k]) =
          *reinterpret_cast<const float4*>(&hs[(long)(t0 + tok) * 2048 + k]);
    }
    __syncthreads();
    int h = tid & 63, tg = tid >> 6;
    float a0 = 0.f, a1 = 0.f, a2 = 0.f, a3 = 0.f;
    const float* wcol = Win + 8448 + h;
    for (int k = 0; k < 2048; k += 4) {
      a0 = fmaf(Xs[tg][k + 0], wcol[(long)(k + 0) * 8512], a0);
      a1 = fmaf(Xs[tg][k + 1], wcol[(long)(k + 1) * 8512], a1);
      a2 = fmaf(Xs[tg][k + 2], wcol[(long)(k + 2) * 8512], a2);
      a3 = fmaf(Xs[tg][k + 3], wcol[(long)(k + 3) * 8512], a3);
    }
    zf[(long)(t0 + tg) * 64 + h] = (a0 + a1) + (a2 + a3);
  } else if (bid < 9216) {
    // ---- cast X -> fp16
    long i = ((long)(bid - 1024) * 256 + tid) * 4;
    float4 v = *reinterpret_cast<const float4*>(hs + i);
    ushort4 u;
    u.x = f2h(v.x); u.y = f2h(v.y); u.z = f2h(v.z); u.w = f2h(v.w);
    *reinterpret_cast<ushort4*>((unsigned short*)Ah + i) = u;
  } else {
    // ---- transpose Win cols [0,8448) -> fp16 [n][k]
    float (*tile)[33] = reinterpret_cast<float (*)[33]>(smemP);
    int i = bid - 9216;
    int c0 = (i % 264) * 32, r0 = (i / 264) * 32;
    int tx = tid & 31, ty = tid >> 5;
#pragma unroll
    for (int j = 0; j < 4; j++)
      tile[ty + j * 8][tx] = Win[(long)(r0 + ty + j * 8) * 8512 + c0 + tx];
    __syncthreads();
#pragma unroll
    for (int j = 0; j < 4; j++) {
      int c = c0 + ty + j * 8, r = r0 + tx;
      WtH[(long)c * 2048 + r] = (_Float16)tile[tx][ty + j * 8];
    }
  }
}

// ===================== in_proj GEMM: 256^2 tile, BK=64, 8-wave 8-phase =======
__global__ __launch_bounds__(512, 2) void gemm_in8(const _Float16* __restrict__ A,
                                                   const _Float16* __restrict__ Bt,
                                                   _Float16* __restrict__ gate,
                                                   float* __restrict__ hbcf,
                                                   float* __restrict__ rparts) {
  __shared__ __attribute__((aligned(128))) char ldsB[131072];
  const int tid = threadIdx.x;
  const int lane = tid & 63;
  const int wv = tid >> 6;
  const int wr = wv >> 2, wc = wv & 3;  // 2 (M) x 4 (N) waves; wave C = 128x64
  const int wg = blockIdx.x;
  const bool rem = wg >= 512;
  int by, bxn, kbase, zz;
  if (!rem) {  // square per-XCD mapping: XCD (wg&7) owns 8(by) x 8(bxn)
    const int xcd = wg & 7, j = wg >> 3;
    by = (xcd >> 2) * 8 + (j >> 3);
    bxn = (xcd & 3) * 8 + (j & 7);
    kbase = 0; zz = 0;
  } else {
    const int idx = wg - 512;
    by = idx & 15; zz = idx >> 4; bxn = 32; kbase = zz * 256;
  }

  const int srow = tid >> 3;
  const int scolg = (tid & 7) ^ (srow & 7);  // inverse-swizzled source col16
  const _Float16* Ab = A + (long)by * 524288 + (long)srow * 2048 + scolg * 8 + kbase;
  const _Float16* Bb = Bt + (long)bxn * 524288 + (long)srow * 2048 + scolg * 8 + kbase;
  const int ldst = tid << 4;

#define STAGE_A(tau, h) do {                                              \
    const _Float16* g_ = Ab + (long)(h) * 262144 + (tau) * 64;            \
    char* l_ = ldsB + ((((tau) & 1) << 2) + (h)) * 16384 + ldst;          \
    GLD16(g_, l_); GLD16(g_ + 131072, l_ + 8192); } while (0)
#define STAGE_B(tau, h) do {                                              \
    const _Float16* g_ = Bb + (long)(h) * 262144 + (tau) * 64;            \
    char* l_ = ldsB + ((((tau) & 1) << 2) + 2 + (h)) * 16384 + ldst;      \
    GLD16(g_, l_); GLD16(g_ + 131072, l_ + 8192); } while (0)

  const int fr = lane & 15;
  const int c16 = (lane >> 4) ^ (fr & 7);
  const int aOff0 = wr * 16384 + fr * 128 + c16 * 16;
  const int aOff1 = aOff0 ^ 64;
  const int bOff0 = (2 + (wc >> 1)) * 16384 + ((wc & 1) * 64 + fr) * 128 + c16 * 16;
  const int bOff1 = bOff0 ^ 64;
#define RD_A(b, mi, k32) (*(const f16x8*)(ldsB + ((k32) ? aOff1 : aOff0) + (b) * 65536 + (mi) * 2048))
#define RD_B(b, ni, k32) (*(const f16x8*)(ldsB + ((k32) ? bOff1 : bOff0) + (b) * 65536 + (ni) * 2048))

#define BAR() __builtin_amdgcn_s_barrier()
#define WLG0() asm volatile("s_waitcnt lgkmcnt(0)" ::: "memory")
#define WLG8() asm volatile("s_waitcnt lgkmcnt(8)" ::: "memory")
#define WVM4() asm volatile("s_waitcnt vmcnt(4)" ::: "memory")

  f32x4 acc[8][4];
#pragma unroll
  for (int mi = 0; mi < 8; ++mi)
#pragma unroll
    for (int ni = 0; ni < 4; ++ni) acc[mi][ni] = f32x4{0.f, 0.f, 0.f, 0.f};

  STAGE_A(0, 0); STAGE_A(0, 1); STAGE_B(0, 0); STAGE_B(0, 1);
  STAGE_B(1, 0); STAGE_B(1, 1);
  WVM4(); BAR();

#define MFMA_Q(MI0, MI1, x0, x1, x2, x3, PB)                                        \
  __builtin_amdgcn_s_setprio(1);                                                    \
  _Pragma("unroll") for (int ni = 0; ni < 4; ++ni) {                                \
    acc[MI0][ni] = __builtin_amdgcn_mfma_f32_16x16x32_f16(x0, PB[ni][0], acc[MI0][ni], 0, 0, 0); \
    acc[MI0][ni] = __builtin_amdgcn_mfma_f32_16x16x32_f16(x1, PB[ni][1], acc[MI0][ni], 0, 0, 0); \
    acc[MI1][ni] = __builtin_amdgcn_mfma_f32_16x16x32_f16(x2, PB[ni][0], acc[MI1][ni], 0, 0, 0); \
    acc[MI1][ni] = __builtin_amdgcn_mfma_f32_16x16x32_f16(x3, PB[ni][1], acc[MI1][ni], 0, 0, 0); \
  }                                                                                 \
  __builtin_amdgcn_s_setprio(0);

#define ITER8(u, msk) do {                                                          \
    const int t1 = (2 * (u) + 1) & (msk);                                           \
    const int t2 = (2 * (u) + 2) & (msk);                                           \
    const int t3 = (2 * (u) + 3) & (msk);                                           \
    f16x8 PB0[4][2];                                                                \
    _Pragma("unroll") for (int ni = 0; ni < 4; ++ni) {                              \
      PB0[ni][0] = RD_B(0, ni, 0); PB0[ni][1] = RD_B(0, ni, 1); }                   \
    {                                                                               \
      f16x8 x0 = RD_A(0, 0, 0), x1 = RD_A(0, 0, 1), x2 = RD_A(0, 1, 0), x3 = RD_A(0, 1, 1); \
      STAGE_A(t1, 0); WLG8(); BAR(); WLG0();                                        \
      MFMA_Q(0, 1, x0, x1, x2, x3, PB0) BAR();                                      \
    }                                                                               \
    {                                                                               \
      f16x8 x0 = RD_A(0, 2, 0), x1 = RD_A(0, 2, 1), x2 = RD_A(0, 3, 0), x3 = RD_A(0, 3, 1); \
      STAGE_A(t1, 1); BAR(); WLG0();                                                \
      MFMA_Q(2, 3, x0, x1, x2, x3, PB0) BAR();                                      \
    }                                                                               \
    {                                                                               \
      f16x8 x0 = RD_A(0, 4, 0), x1 = RD_A(0, 4, 1), x2 = RD_A(0, 5, 0), x3 = RD_A(0, 5, 1); \
      STAGE_B(t2, 0); BAR(); WLG0();                                                \
      MFMA_Q(4, 5, x0, x1, x2, x3, PB0) BAR();                                      \
    }                                                                               \
    {                                                                               \
      f16x8 x0 = RD_A(0, 6, 0), x1 = RD_A(0, 6, 1), x2 = RD_A(0, 7, 0), x3 = RD_A(0, 7, 1); \
      STAGE_B(t2, 1); BAR(); WLG0();                                                \
      MFMA_Q(6, 7, x0, x1, x2, x3, PB0) WVM4(); BAR();                              \
    }                                                                               \
    f16x8 PB1[4][2];                                                                \
    _Pragma("unroll") for (int ni = 0; ni < 4; ++ni) {                              \
      PB1[ni][0] = RD_B(1, ni, 0); PB1[ni][1] = RD_B(1, ni, 1); }                   \
    {                                                                               \
      f16x8 x0 = RD_A(1, 0, 0), x1 = RD_A(1, 0, 1), x2 = RD_A(1, 1, 0), x3 = RD_A(1, 1, 1); \
      STAGE_A(t2, 0); WLG8(); BAR(); WLG0();                                        \
      MFMA_Q(0, 1, x0, x1, x2, x3, PB1) BAR();                                      \
    }                                                                               \
    {                                                                               \
      f16x8 x0 = RD_A(1, 2, 0), x1 = RD_A(1, 2, 1), x2 = RD_A(1, 3, 0), x3 = RD_A(1, 3, 1); \
      STAGE_A(t2, 1); BAR(); WLG0();                                                \
      MFMA_Q(2, 3, x0, x1, x2, x3, PB1) BAR();                                      \
    }                                                                               \
    {                                                                               \
      f16x8 x0 = RD_A(1, 4, 0), x1 = RD_A(1, 4, 1), x2 = RD_A(1, 5, 0), x3 = RD_A(1, 5, 1); \
      STAGE_B(t3, 0); BAR(); WLG0();                                                \
      MFMA_Q(4, 5, x0, x1, x2, x3, PB1) BAR();                                      \
    }                                                                               \
    {                                                                               \
      f16x8 x0 = RD_A(1, 6, 0), x1 = RD_A(1, 6, 1), x2 = RD_A(1, 7, 0), x3 = RD_A(1, 7, 1); \
      STAGE_B(t3, 1); BAR(); WLG0();                                                \
      MFMA_Q(6, 7, x0, x1, x2, x3, PB1) WVM4(); BAR();                              \
    }                                                                               \
  } while (0)

  if (!rem) {
    for (int u = 0; u < 16; ++u) ITER8(u, 31);
  } else {
    for (int u = 0; u < 2; ++u) ITER8(u, 3);
  }

  const int m0 = by * 256 + wr * 128;
  const int cl = lane & 15, rq = (lane >> 4) * 4;
  if (!rem) {
    const int n0 = bxn * 256 + wc * 64;
    if (bxn < 16) {
#pragma unroll
      for (int mi = 0; mi < 8; ++mi)
#pragma unroll
        for (int r = 0; r < 4; ++r) {
          long rowoff = (long)(m0 + mi * 16 + rq + r) * 4096 + n0 + cl;
#pragma unroll
          for (int ni = 0; ni < 4; ++ni) gate[rowoff + ni * 16] = (_Float16)acc[mi][ni][r];
        }
    } else {
#pragma unroll
      for (int mi = 0; mi < 8; ++mi)
#pragma unroll
        for (int r = 0; r < 4; ++r) {
          long rowoff = (long)(m0 + mi * 16 + rq + r) * 4352 + (n0 - 4096) + cl;
#pragma unroll
          for (int ni = 0; ni < 4; ++ni) hbcf[rowoff + ni * 16] = acc[mi][ni][r];
        }
    }
  } else {
    float* rp = rparts + (long)zz * 1048576;
    const int ncol = wc * 64;
#pragma unroll
    for (int mi = 0; mi < 8; ++mi)
#pragma unroll
      for (int r = 0; r < 4; ++r) {
        long rowoff = (long)(m0 + mi * 16 + rq + r) * 256 + ncol + cl;
#pragma unroll
        for (int ni = 0; ni < 4; ++ni) rp[rowoff + ni * 16] = acc[mi][ni][r];
      }
  }
#undef STAGE_A
#undef STAGE_B
#undef RD_A
#undef RD_B
#undef ITER8
}

// == fuse2: dt_cum (16) || add_rem (1024) || transpose_wout*nw (8192) =========
__global__ __launch_bounds__(256) void fuse2(const float* __restrict__ zf,
                                             const float* __restrict__ dtb,
                                             const float* __restrict__ Alog,
                                             float* __restrict__ dt_f,
                                             float* __restrict__ cum_f,
                                             float* __restrict__ cuml,
                                             const float* __restrict__ rp,
                                             float* __restrict__ hbcf,
                                             const float* __restrict__ Wout,
                                             const float* __restrict__ nw,
                                             _Float16* __restrict__ WoutT) {
  __shared__ __attribute__((aligned(16))) char smem2[4352];
  const int bid = blockIdx.x;
  const int tid = threadIdx.x;
  if (bid < 16) {
    float (*segsum)[64] = reinterpret_cast<float (*)[64]>(smem2);
    int bc = bid;
    int h = tid & 63, seg = tid >> 6;
    int t0 = bc * 256;
    float Ah = -expf(Alog[h]);
    float bias = dtb[h];
    float s = 0.f;
    for (int j = 0; j < 64; j++) {
      int t = t0 + seg * 64 + j;
      float z = zf[(long)t * 64 + h] + bias;
      float v = (z > 20.f) ? z : log1pf(expf(z));
      dt_f[(long)t * 64 + h] = v;
      s += v * Ah;
    }
    segsum[seg][h] = s;
    __syncthreads();
    float run = 0.f;
    for (int k = 0; k < seg; k++) run += segsum[k][h];
    for (int j = 0; j < 64; j++) {
      int t = t0 + seg * 64 + j;
      run += dt_f[(long)t * 64 + h] * Ah;
      cum_f[(long)t * 64 + h] = run;
    }
    if (seg == 3) cuml[bc * 64 + h] = run;
  } else if (bid < 1040) {
    long e = ((long)(bid - 16) * 256 + tid) * 4;
    float4 s = *reinterpret_cast<const float4*>(rp + e);
#pragma unroll
    for (int z = 1; z < 8; ++z) {
      float4 v = *reinterpret_cast<const float4*>(rp + (long)z * 1048576 + e);
      s.x += v.x; s.y += v.y; s.z += v.z; s.w += v.w;
    }
    long row = e >> 8, col = e & 255;
    *reinterpret_cast<float4*>(hbcf + row * 4352 + 4096 + col) = s;
  } else {
    // transpose+cast Wout [4096,2048] -> WoutT [2048][4096], nw folded in.
    float (*tile)[33] = reinterpret_cast<float (*)[33]>(smem2);
    int i = bid - 1040;
    int c0 = (i & 63) * 32, r0 = (i >> 6) * 32;
    int tx = tid & 31, ty = tid >> 5;
#pragma unroll
    for (int j = 0; j < 4; j++)
      tile[ty + j * 8][tx] = Wout[(long)(r0 + ty + j * 8) * 2048 + c0 + tx];
    __syncthreads();
    float nwr = nw[r0 + tx];
#pragma unroll
    for (int j = 0; j < 4; j++) {
      int c = c0 + ty + j * 8, r = r0 + tx;
      WoutT[(long)c * 4096 + r] = (_Float16)(tile[tx][ty + j * 8] * nwr);
    }
  }
}

// ======= convx: conv(K=4)+SiLU fused with transposes: x->xT16, B->BT16 =======
__global__ __launch_bounds__(256) void convx(const float* __restrict__ hbcf,
                                             const float* __restrict__ convw,
                                             const float* __restrict__ convb,
                                             _Float16* __restrict__ x16,
                                             _Float16* __restrict__ B16,
                                             _Float16* __restrict__ C16,
                                             unsigned short* __restrict__ xT16,
                                             unsigned short* __restrict__ BT16) {
  __shared__ unsigned short tile[64][66];
  const int bx = blockIdx.x, t0 = blockIdx.y * 64;
  const int tid = threadIdx.x;
  const int tq = tid & 63, tg = tid >> 6;
  const int q0 = (bx < 64) ? bx * 64 : 4096 + (bx - 64) * 64;
  const int q = q0 + tq;
  const int ts = t0 + tg * 16;
  const int bstart = ts & ~2047;
  const float* colq = hbcf + q;
  float4 wq = *reinterpret_cast<const float4*>(convw + q * 4);
  float bconv = convb[q];
  float v3 = (ts - 3 >= bstart) ? colq[(long)(ts - 3) * 4352] : 0.f;
  float v2 = (ts - 2 >= bstart) ? colq[(long)(ts - 2) * 4352] : 0.f;
  float v1 = (ts - 1 >= bstart) ? colq[(long)(ts - 1) * 4352] : 0.f;
  if (bx < 64) {
#pragma unroll
    for (int j = 0; j < 16; ++j) {
      int t = ts + j;
      float v0 = colq[(long)t * 4352];
      float a = bconv + v3 * wq.x + v2 * wq.y + v1 * wq.z + v0 * wq.w;
      unsigned short o = f2h(siluf(a));
      ((unsigned short*)x16)[(long)t * 4096 + q] = o;
      tile[tg * 16 + j][tq] = o;
      v3 = v2; v2 = v1; v1 = v0;
    }
    __syncthreads();
    int tx = tid & 15, ty = tid >> 4;
#pragma unroll
    for (int i = 0; i < 4; ++i) {
      int c = ty + i * 16;
      ushort4 v;
      v.x = tile[4 * tx + 0][c]; v.y = tile[4 * tx + 1][c];
      v.z = tile[4 * tx + 2][c]; v.w = tile[4 * tx + 3][c];
      *(ushort4*)&xT16[(long)(q0 + c) * 4096 + t0 + 4 * tx] = v;
    }
  } else if (bx < 66) {
    // B cols: row-major B16 + transposed BT16[n][t]
    const int n0 = q0 - 4096;
#pragma unroll
    for (int j = 0; j < 16; ++j) {
      int t = ts + j;
      float v0 = colq[(long)t * 4352];
      float a = bconv + v3 * wq.x + v2 * wq.y + v1 * wq.z + v0 * wq.w;
      unsigned short o = f2h(siluf(a));
      ((unsigned short*)B16)[(long)t * 128 + (q - 4096)] = o;
      tile[tg * 16 + j][tq] = o;
      v3 = v2; v2 = v1; v1 = v0;
    }
    __syncthreads();
    int tx = tid & 15, ty = tid >> 4;
#pragma unroll
    for (int i = 0; i < 4; ++i) {
      int c = ty + i * 16;
      ushort4 v;
      v.x = tile[4 * tx + 0][c]; v.y = tile[4 * tx + 1][c];
      v.z = tile[4 * tx + 2][c]; v.w = tile[4 * tx + 3][c];
      *(ushort4*)&BT16[(long)(n0 + c) * 4096 + t0 + 4 * tx] = v;
    }
  } else {
#pragma unroll
    for (int j = 0; j < 16; ++j) {
      int t = ts + j;
      float v0 = colq[(long)t * 4352];
      float a = bconv + v3 * wq.x + v2 * wq.y + v1 * wq.z + v0 * wq.w;
      _Float16 o = (_Float16)siluf(a);
      C16[(long)t * 128 + (q - 4224)] = o;
      v3 = v2; v2 = v1; v1 = v0;
    }
  }
}

// ========= fuse3: states_mfma (1024) || CBTt gemm (64) || ssq zero (4) =======
__global__ __launch_bounds__(256) void fuse3(const unsigned short* __restrict__ xT16,
                                             const unsigned short* __restrict__ BT16,
                                             const _Float16* __restrict__ B16,
                                             const _Float16* __restrict__ C16,
                                             const float* __restrict__ dt_f,
                                             const float* __restrict__ cum_f,
                                             const float* __restrict__ cuml,
                                             float* __restrict__ states,
                                             float* __restrict__ CBT,
                                             float* __restrict__ ssq) {
  __shared__ __attribute__((aligned(16))) char smem3[16384];
  const int bid = blockIdx.x;
  const int tid = threadIdx.x;
  const int wv = tid >> 6, lane = tid & 63;
  const int mr = lane & 15, koff = (lane >> 4) * 8;
  if (bid < 1024) {
    float* w_s = (float*)smem3;
    unsigned short* Aw = (unsigned short*)(smem3 + 1024);
    int h = bid & 63, bc = bid >> 6;
    int t0 = bc * 256;
    {
      int t = t0 + tid;
      w_s[tid] = expf(cuml[bc * 64 + h] - cum_f[(long)t * 64 + h]) * dt_f[(long)t * 64 + h];
    }
    __syncthreads();
    f32x4 acc[4][2];
#pragma unroll
    for (int mi = 0; mi < 4; mi++)
#pragma unroll
      for (int nj = 0; nj < 2; nj++) acc[mi][nj] = f32x4{0.f, 0.f, 0.f, 0.f};
    const unsigned short* btb = BT16 + t0 + koff;
    for (int kt = 0; kt < 8; kt++) {
      {
        int p = tid >> 2, tq2 = tid & 3;
        const unsigned short* g = &xT16[((long)(h * 64 + p)) * 4096 + t0 + kt * 32 + tq2 * 8];
        ushort4 u0 = *(const ushort4*)g, u1 = *(const ushort4*)(g + 4);
        const float* wp = &w_s[kt * 32 + tq2 * 8];
        ushort4 o0, o1;
        o0.x = f2h(h2f(u0.x) * wp[0]); o0.y = f2h(h2f(u0.y) * wp[1]);
        o0.z = f2h(h2f(u0.z) * wp[2]); o0.w = f2h(h2f(u0.w) * wp[3]);
        o1.x = f2h(h2f(u1.x) * wp[4]); o1.y = f2h(h2f(u1.y) * wp[5]);
        o1.z = f2h(h2f(u1.z) * wp[6]); o1.w = f2h(h2f(u1.w) * wp[7]);
        *(ushort4*)&Aw[p * 40 + tq2 * 8] = o0;
        *(ushort4*)&Aw[p * 40 + tq2 * 8 + 4] = o1;
      }
      __syncthreads();
      f16x8 af[4], bf[2];
#pragma unroll
      for (int mi = 0; mi < 4; mi++)
        af[mi] = *(const f16x8*)&Aw[(mi * 16 + mr) * 40 + koff];
#pragma unroll
      for (int nj = 0; nj < 2; nj++)
        bf[nj] = *(const f16x8*)(btb + (long)((wv * 2 + nj) * 16 + mr) * 4096 + kt * 32);
#pragma unroll
      for (int mi = 0; mi < 4; mi++)
#pragma unroll
        for (int nj = 0; nj < 2; nj++)
          acc[mi][nj] = __builtin_amdgcn_mfma_f32_16x16x32_f16(af[mi], bf[nj],
                                                               acc[mi][nj], 0, 0, 0);
      __syncthreads();
    }
    int cl = lane & 15, rq = (lane >> 4) * 4;
    long base = ((long)(bc * 64 + h)) * 8192;
#pragma unroll
    for (int mi = 0; mi < 4; mi++)
#pragma unroll
      for (int r = 0; r < 4; r++) {
        int p = mi * 16 + rq + r;
#pragma unroll
        for (int nj = 0; nj < 2; nj++) {
          int n = (wv * 2 + nj) * 16 + cl;
          states[base + p * 128 + n] = acc[mi][nj][r];
        }
      }
  } else if (bid < 1088) {
    _Float16* As = (_Float16*)smem3;
    _Float16* Bs = (_Float16*)(smem3 + 8192);
    int i = bid - 1024;
    int bx = i & 1, by = (i >> 1) & 1, bz = i >> 2;
    // TRANSPOSED production: A = B16 rows (j), B = C16 rows (i)
    const _Float16* Ab = B16 + (long)bz * 32768 + (long)by * 128 * 128;
    const _Float16* Bb = C16 + (long)bz * 32768 + (long)bx * 128 * 128;
    const int c0 = wv * 128 + lane;
    const int c1 = c0 + 64;
    const long ra0 = (long)(c0 >> 2) * 128 + (c0 & 3) * 8;
    const long ra1 = (long)(c1 >> 2) * 128 + (c1 & 3) * 8;
    f32x4 acc[4][4];
#pragma unroll
    for (int mi = 0; mi < 4; mi++)
#pragma unroll
      for (int ni = 0; ni < 4; ni++) acc[mi][ni] = f32x4{0.f, 0.f, 0.f, 0.f};
    const int mrow = (wv & 1) * 64 + (lane & 15);
    const int nrow = (wv >> 1) * 64 + (lane & 15);
    for (int k0 = 0; k0 < 128; k0 += 32) {
      GLD16(Ab + ra0 + k0, (char*)As + c0 * 16);
      GLD16(Ab + ra1 + k0, (char*)As + c1 * 16);
      GLD16(Bb + ra0 + k0, (char*)Bs + c0 * 16);
      GLD16(Bb + ra1 + k0, (char*)Bs + c1 * 16);
      __syncthreads();
      f16x8 af[4], bfr[4];
#pragma unroll
      for (int mi = 0; mi < 4; mi++)
        af[mi] = *(const f16x8*)(As + (mrow + mi * 16) * 32 + koff);
#pragma unroll
      for (int ni = 0; ni < 4; ni++)
        bfr[ni] = *(const f16x8*)(Bs + (nrow + ni * 16) * 32 + koff);
#pragma unroll
      for (int mi = 0; mi < 4; mi++)
#pragma unroll
        for (int ni = 0; ni < 4; ni++)
          acc[mi][ni] = __builtin_amdgcn_mfma_f32_16x16x32_f16(af[mi], bfr[ni],
                                                               acc[mi][ni], 0, 0, 0);
      __syncthreads();
    }
    const int m0 = by * 128 + (wv & 1) * 64;
    const int n0 = bx * 128 + (wv >> 1) * 64;
    const int cl = lane & 15, rq = (lane >> 4) * 4;
    const long zc = (long)bz * 65536;
#pragma unroll
    for (int mi = 0; mi < 4; mi++)
#pragma unroll
      for (int r = 0; r < 4; r++) {
        long rowoff = zc + (long)(m0 + mi * 16 + rq + r) * 256 + n0 + cl;
#pragma unroll
        for (int ni = 0; ni < 4; ni++) CBT[rowoff + ni * 16] = acc[mi][ni][r];
      }
  } else {
    // zero ssq[4096]
    int i = (bid - 1088) * 1024 + tid * 4;
    *reinterpret_cast<float4*>(&ssq[i]) = make_float4(0.f, 0.f, 0.f, 0.f);
  }
}

// ------------- inter-chunk recurrence (1024 blocks: 128 bh x 8 j-slices) -----
__global__ __launch_bounds__(256) void recur_kernel(float* __restrict__ states,
                                                    const float* __restrict__ cuml) {
  int g = blockIdx.x;
  int bh = g >> 3, js = g & 7;
  int b = bh >> 6, h = bh & 63;
  int tid = threadIdx.x;
  float4 prev = make_float4(0.f, 0.f, 0.f, 0.f);
  for (int c = 0; c < 8; c++) {
    int bc = b * 8 + c;
    float cd = expf(cuml[bc * 64 + h]);
    long o = (long)(bc * 64 + h) * 8192 + js * 1024 + tid * 4;
    float4 st = *reinterpret_cast<const float4*>(&states[o]);
    *reinterpret_cast<float4*>(&states[o]) = prev;
    prev.x = fmaf(cd, prev.x, st.x);
    prev.y = fmaf(cd, prev.y, st.y);
    prev.z = fmaf(cd, prev.z, st.z);
    prev.w = fmaf(cd, prev.w, st.w);
  }
}

// ---------------- fused Y = Ydiag + Yoff + D*x, then *SiLU(gate) -> hid fp16
// (un-normalized; RMS scale folded downstream). One barrier; CBTt coalesced;
// exp2 on pre-scaled cums; wave-self-owned Sb rows; causal formation skip.
__global__ __launch_bounds__(256) void yfused(const unsigned short* __restrict__ xT16,
                                              const unsigned short* __restrict__ x16,
                                              const unsigned short* __restrict__ C16,
                                              const unsigned short* __restrict__ gate,
                                              const float* __restrict__ CBTt,
                                              const float* __restrict__ states,
                                              const float* __restrict__ dt_f,
                                              const float* __restrict__ cum_f,
                                              const float* __restrict__ Dp,
                                              unsigned short* __restrict__ hid,
                                              float* __restrict__ ssq) {
  int h = blockIdx.x, bc = blockIdx.y;
  int t0 = bc * 256, tid = threadIdx.x;
  __shared__ unsigned short Sb[256 * 40];   // 20480: per-wave-owned S / Afac
  __shared__ unsigned short Xb[64 * 264];   // 33792: xT tile (coalesced staging)
  __shared__ unsigned short PS[64 * 136];   // 17408: states fp16
  __shared__ float c2_s[256], dt_s[256];    // 2048  (total 73728)
  int i = tid;
  c2_s[i] = cum_f[(long)(t0 + i) * 64 + h] * 1.44269504f;
  dt_s[i] = dt_f[(long)(t0 + i) * 64 + h];
  {  // stage xT tile
    int p = tid >> 2, tq = tid & 3;
    const unsigned short* g = &xT16[((long)(h * 64 + p)) * 4096 + t0 + tq * 64];
    unsigned short* l = &Xb[p * 264 + tq * 64];
#pragma unroll
    for (int c = 0; c < 8; c++)
      *(uint4*)(l + c * 8) = *(const uint4*)(g + c * 8);
  }
  {  // stage PS16 (states -> fp16)
    int p = tid >> 2, nq = tid & 3;
    const float* g = &states[((long)(bc * 64 + h)) * 8192 + p * 128 + nq * 32];
    unsigned short* l = &PS[p * 136 + nq * 32];
#pragma unroll
    for (int c = 0; c < 8; c++) {
      float4 v = *(const float4*)(g + c * 4);
      ushort4 u;
      u.x = f2h(v.x); u.y = f2h(v.y); u.z = f2h(v.z); u.w = f2h(v.w);
      *(ushort4*)(l + c * 4) = u;
    }
  }
  __syncthreads();  // the ONLY barrier
  float c2_i = c2_s[i];
  const float* cbcol = CBTt + (long)bc * 65536 + i;  // lane-coalesced column
  int wv = tid >> 6, lane = tid & 63;
  int mr = lane & 15, koff = (lane >> 4) * 8;
  f32x4 acc[4][4];
#pragma unroll
  for (int mi = 0; mi < 4; mi++)
#pragma unroll
    for (int ni = 0; ni < 4; ni++) acc[mi][ni] = f32x4{0.f, 0.f, 0.f, 0.f};
  // ---------------- ydiag: per-wave causal range, barrier-free
  const int ktmax = 2 * wv + 2;
  for (int kt = 0; kt < ktmax; kt++) {
    int k0 = kt * 32;
#pragma unroll
    for (int c = 0; c < 8; c++) {
      int jb = k0 + c * 4;
      float cb0 = cbcol[(long)(jb + 0) * 256];
      float cb1 = cbcol[(long)(jb + 1) * 256];
      float cb2 = cbcol[(long)(jb + 2) * 256];
      float cb3 = cbcol[(long)(jb + 3) * 256];
      ushort4 o;
      o.x = f2h((jb + 0 <= i) ? cb0 * exp2f(c2_i - c2_s[jb + 0]) * dt_s[jb + 0] : 0.f);
      o.y = f2h((jb + 1 <= i) ? cb1 * exp2f(c2_i - c2_s[jb + 1]) * dt_s[jb + 1] : 0.f);
      o.z = f2h((jb + 2 <= i) ? cb2 * exp2f(c2_i - c2_s[jb + 2]) * dt_s[jb + 2] : 0.f);
      o.w = f2h((jb + 3 <= i) ? cb3 * exp2f(c2_i - c2_s[jb + 3]) * dt_s[jb + 3] : 0.f);
      *(ushort4*)&Sb[i * 40 + c * 4] = o;
    }
    f16x8 af[4], bf[4];
#pragma unroll
    for (int mi = 0; mi < 4; mi++)
      af[mi] = *(const f16x8*)&Sb[(64 * wv + mi * 16 + mr) * 40 + koff];
#pragma unroll
    for (int ni = 0; ni < 4; ni++)
      bf[ni] = *(const f16x8*)&Xb[(ni * 16 + mr) * 264 + k0 + koff];
#pragma unroll
    for (int mi = 0; mi < 4; mi++)
#pragma unroll
      for (int ni = 0; ni < 4; ni++)
        acc[mi][ni] = __builtin_amdgcn_mfma_f32_16x16x32_f16(af[mi], bf[ni],
                                                             acc[mi][ni], 0, 0, 0);
  }
  // ---------------- yoff: barrier-free (PS staged up-front)
  float fac_i = exp2f(c2_i);
  for (int kn = 0; kn < 4; kn++) {
    {  // form Afac row i
      const unsigned short* g = &C16[((long)(t0 + i)) * 128 + kn * 32];
#pragma unroll
      for (int c = 0; c < 8; c++) {
        ushort4 u = *(const ushort4*)(g + c * 4);
        ushort4 o;
        o.x = f2h(h2f(u.x) * fac_i); o.y = f2h(h2f(u.y) * fac_i);
        o.z = f2h(h2f(u.z) * fac_i); o.w = f2h(h2f(u.w) * fac_i);
        *(ushort4*)&Sb[i * 40 + c * 4] = o;
      }
    }
    f16x8 af[4], bf[4];
#pragma unroll
    for (int mi = 0; mi < 4; mi++)
      af[mi] = *(const f16x8*)&Sb[(64 * wv + mi * 16 + mr) * 40 + koff];
#pragma unroll
    for (int ni = 0; ni < 4; ni++)
      bf[ni] = *(const f16x8*)&PS[(ni * 16 + mr) * 136 + kn * 32 + koff];
#pragma unroll
    for (int mi = 0; mi < 4; mi++)
#pragma unroll
      for (int ni = 0; ni < 4; ni++)
        acc[mi][ni] = __builtin_amdgcn_mfma_f32_16x16x32_f16(af[mi], bf[ni],
                                                             acc[mi][ni], 0, 0, 0);
  }
  // epilogue: y = acc + D*x; h = y*silu(gate); store fp16 + per-row ssq
  float Dh = Dp[h];
  int cl = lane & 15, rq = (lane >> 4) * 4;
#pragma unroll
  for (int mi = 0; mi < 4; mi++)
#pragma unroll
    for (int r = 0; r < 4; r++) {
      long row = t0 + 64 * wv + mi * 16 + rq + r;
      const unsigned short* xr = &x16[row * 4096 + h * 64];
      const unsigned short* gr = &gate[row * 4096 + h * 64];
      unsigned short* hw = &hid[row * 4096 + h * 64];
      float ssp = 0.f;
#pragma unroll
      for (int ni = 0; ni < 4; ni++) {
        int p = ni * 16 + cl;
        float yv = acc[mi][ni][r] + Dh * h2f(xr[p]);
        float hv = yv * siluf(h2f(gr[p]));
        hw[p] = f2h(hv);
        ssp += hv * hv;
      }
#pragma unroll
      for (int o = 8; o > 0; o >>= 1) ssp += __shfl_down(ssp, o, 16);
      if (cl == 0) atomicAdd(&ssq[row], ssp);
    }
}

// ===================== out_proj GEMM: 256^2 tile, split-K (z=2), 8-phase =====
__global__ __launch_bounds__(512, 2) void gemm_out8(const _Float16* __restrict__ A,
                                                    const _Float16* __restrict__ Bt,
                                                    float* __restrict__ Cp0,
                                                    float* __restrict__ Cp1) {
  __shared__ __attribute__((aligned(128))) char ldsB[131072];
  const int tid = threadIdx.x;
  const int lane = tid & 63;
  const int wv = tid >> 6;
  const int wr = wv >> 2, wc = wv & 3;
  const int wg = blockIdx.x;
  const int xcd = wg & 7, j = wg >> 3;   // j in [0,32)
  const int z = j >> 4, t = j & 15;
  const int by = (xcd >> 1) * 4 + (t >> 2);
  const int bx = (xcd & 1) * 4 + (t & 3);

  const int srow = tid >> 3;
  const int scolg = (tid & 7) ^ (srow & 7);
  const _Float16* Ab = A + (long)by * 256 * 4096 + (long)z * 2048 +
                       (long)srow * 4096 + scolg * 8;
  const _Float16* Bb = Bt + (long)bx * 256 * 4096 + (long)z * 2048 +
                       (long)srow * 4096 + scolg * 8;
  const int ldst = tid << 4;

#define STAGE_A(tau, h) do {                                              \
    const _Float16* g_ = Ab + (long)(h) * 524288 + (tau) * 64;            \
    char* l_ = ldsB + ((((tau) & 1) << 2) + (h)) * 16384 + ldst;          \
    GLD16(g_, l_); GLD16(g_ + 262144, l_ + 8192); } while (0)
#define STAGE_B(tau, h) do {                                              \
    const _Float16* g_ = Bb + (long)(h) * 524288 + (tau) * 64;            \
    char* l_ = ldsB + ((((tau) & 1) << 2) + 2 + (h)) * 16384 + ldst;      \
    GLD16(g_, l_); GLD16(g_ + 262144, l_ + 8192); } while (0)

  const int fr = lane & 15;
  const int c16 = (lane >> 4) ^ (fr & 7);
  const int aOff0 = wr * 16384 + fr * 128 + c16 * 16;
  const int aOff1 = aOff0 ^ 64;
  const int bOff0 = (2 + (wc >> 1)) * 16384 + ((wc & 1) * 64 + fr) * 128 + c16 * 16;
  const int bOff1 = bOff0 ^ 64;
#define RD_A(b, mi, k32) (*(const f16x8*)(ldsB + ((k32) ? aOff1 : aOff0) + (b) * 65536 + (mi) * 2048))
#define RD_B(b, ni, k32) (*(const f16x8*)(ldsB + ((k32) ? bOff1 : bOff0) + (b) * 65536 + (ni) * 2048))

#define BAR() __builtin_amdgcn_s_barrier()
#define WLG0() asm volatile("s_waitcnt lgkmcnt(0)" ::: "memory")
#define WLG8() asm volatile("s_waitcnt lgkmcnt(8)" ::: "memory")
#define WVM4() asm volatile("s_waitcnt vmcnt(4)" ::: "memory")

  f32x4 acc[8][4];
#pragma unroll
  for (int mi = 0; mi < 8; ++mi)
#pragma unroll
    for (int ni = 0; ni < 4; ++ni) acc[mi][ni] = f32x4{0.f, 0.f, 0.f, 0.f};

  STAGE_A(0, 0); STAGE_A(0, 1); STAGE_B(0, 0); STAGE_B(0, 1);
  STAGE_B(1, 0); STAGE_B(1, 1);
  WVM4(); BAR();

#define MFMA_Q(MI0, MI1, x0, x1, x2, x3, PB)                                        \
  __builtin_amdgcn_s_setprio(1);                                                    \
  _Pragma("unroll") for (int ni = 0; ni < 4; ++ni) {                                \
    acc[MI0][ni] = __builtin_amdgcn_mfma_f32_16x16x32_f16(x0, PB[ni][0], acc[MI0][ni], 0, 0, 0); \
    acc[MI0][ni] = __builtin_amdgcn_mfma_f32_16x16x32_f16(x1, PB[ni][1], acc[MI0][ni], 0, 0, 0); \
    acc[MI1][ni] = __builtin_amdgcn_mfma_f32_16x16x32_f16(x2, PB[ni][0], acc[MI1][ni], 0, 0, 0); \
    acc[MI1][ni] = __builtin_amdgcn_mfma_f32_16x16x32_f16(x3, PB[ni][1], acc[MI1][ni], 0, 0, 0); \
  }                                                                                 \
  __builtin_amdgcn_s_setprio(0);

  for (int u = 0; u < 16; ++u) {
    const int t1 = 2 * u + 1;
    const int t2 = (2 * u + 2) & 31;
    const int t3 = (2 * u + 3) & 31;
    f16x8 PB0[4][2];
#pragma unroll
    for (int ni = 0; ni < 4; ++ni) { PB0[ni][0] = RD_B(0, ni, 0); PB0[ni][1] = RD_B(0, ni, 1); }
    {
      f16x8 x0 = RD_A(0, 0, 0), x1 = RD_A(0, 0, 1), x2 = RD_A(0, 1, 0), x3 = RD_A(0, 1, 1);
      STAGE_A(t1, 0); WLG8(); BAR(); WLG0();
      MFMA_Q(0, 1, x0, x1, x2, x3, PB0) BAR();
    }
    {
      f16x8 x0 = RD_A(0, 2, 0), x1 = RD_A(0, 2, 1), x2 = RD_A(0, 3, 0), x3 = RD_A(0, 3, 1);
      STAGE_A(t1, 1); BAR(); WLG0();
      MFMA_Q(2, 3, x0, x1, x2, x3, PB0) BAR();
    }
    {
      f16x8 x0 = RD_A(0, 4, 0), x1 = RD_A(0, 4, 1), x2 = RD_A(0, 5, 0), x3 = RD_A(0, 5, 1);
      STAGE_B(t2, 0); BAR(); WLG0();
      MFMA_Q(4, 5, x0, x1, x2, x3, PB0) BAR();
    }
    {
      f16x8 x0 = RD_A(0, 6, 0), x1 = RD_A(0, 6, 1), x2 = RD_A(0, 7, 0), x3 = RD_A(0, 7, 1);
      STAGE_B(t2, 1); BAR(); WLG0();
      MFMA_Q(6, 7, x0, x1, x2, x3, PB0) WVM4(); BAR();
    }
    f16x8 PB1[4][2];
#pragma unroll
    for (int ni = 0; ni < 4; ++ni) { PB1[ni][0] = RD_B(1, ni, 0); PB1[ni][1] = RD_B(1, ni, 1); }
    {
      f16x8 x0 = RD_A(1, 0, 0), x1 = RD_A(1, 0, 1), x2 = RD_A(1, 1, 0), x3 = RD_A(1, 1, 1);
      STAGE_A(t2, 0); WLG8(); BAR(); WLG0();
      MFMA_Q(0, 1, x0, x1, x2, x3, PB1) BAR();
    }
    {
      f16x8 x0 = RD_A(1, 2, 0), x1 = RD_A(1, 2, 1), x2 = RD_A(1, 3, 0), x3 = RD_A(1, 3, 1);
      STAGE_A(t2, 1); BAR(); WLG0();
      MFMA_Q(2, 3, x0, x1, x2, x3, PB1) BAR();
    }
    {
      f16x8 x0 = RD_A(1, 4, 0), x1 = RD_A(1, 4, 1), x2 = RD_A(1, 5, 0), x3 = RD_A(1, 5, 1);
      STAGE_B(t3, 0); BAR(); WLG0();
      MFMA_Q(4, 5, x0, x1, x2, x3, PB1) BAR();
    }
    {
      f16x8 x0 = RD_A(1, 6, 0), x1 = RD_A(1, 6, 1), x2 = RD_A(1, 7, 0), x3 = RD_A(1, 7, 1);
      STAGE_B(t3, 1); BAR(); WLG0();
      MFMA_Q(6, 7, x0, x1, x2, x3, PB1) WVM4(); BAR();
    }
  }
  const int m0 = by * 256 + wr * 128;
  const int n0 = bx * 256 + wc * 64;
  const int cl = lane & 15, rq = (lane >> 4) * 4;
  float* Cb = z ? Cp1 : Cp0;
#pragma unroll
  for (int mi = 0; mi < 8; ++mi)
#pragma unroll
    for (int r = 0; r < 4; ++r) {
      long rowoff = (long)(m0 + mi * 16 + rq + r) * 2048 + n0 + cl;
#pragma unroll
      for (int ni = 0; ni < 4; ++ni) Cb[rowoff + ni * 16] = acc[mi][ni][r];
    }
#undef STAGE_A
#undef STAGE_B
#undef RD_A
#undef RD_B
#undef BAR
#undef WLG0
#undef WLG8
#undef WVM4
#undef MFMA_Q
}

// ------------- sum the two split-K partials, apply RMS row-scale ------------
__global__ __launch_bounds__(256) void add_out(const float* __restrict__ p0,
                                               const float* __restrict__ p1,
                                               const float* __restrict__ ssq,
                                               float* __restrict__ o) {
  long i = ((long)blockIdx.x * 256 + threadIdx.x) * 4;
  float sc = rsqrtf(ssq[i >> 11] * (1.f / 4096.f) + 1e-5f);
  float4 a = *reinterpret_cast<const float4*>(p0 + i);
  float4 b = *reinterpret_cast<const float4*>(p1 + i);
  float4 r;
  r.x = (a.x + b.x) * sc; r.y = (a.y + b.y) * sc;
  r.z = (a.z + b.z) * sc; r.w = (a.w + b.w) * sc;
  *reinterpret_cast<float4*>(o + i) = r;
}

// =============================================================== launch
extern "C" void kernel_launch(void* const* d_in, const int* in_sizes, int n_in,
                              void* d_out, int out_size, void* d_ws, size_t ws_size,
                              hipStream_t stream) {
  (void)in_sizes; (void)n_in; (void)out_size; (void)ws_size;
  const float* hs    = (const float*)d_in[0];
  const float* Win   = (const float*)d_in[1];
  const float* convw = (const float*)d_in[2];
  const float* convb = (const float*)d_in[3];
  const float* dtb   = (const float*)d_in[4];
  const float* Alog  = (const float*)d_in[5];
  const float* Dp    = (const float*)d_in[6];
  const float* nw    = (const float*)d_in[7];
  const float* Wout  = (const float*)d_in[8];
  float* out = (float*)d_out;

  char* base = (char*)d_ws;
  size_t off = 0;
  auto take = [&](size_t n) { char* r = base + off; off += (n + 255) & ~(size_t)255; return r; };
  float*    hbcf  = (float*)take(4096UL * 4352 * 4);    // gemm_in -> conv; then hid (fp16)
  _Float16* gateh = (_Float16*)take(4096UL * 4096 * 2); // gemm_in -> yfused; then oparts1
  _Float16* Ah    = (_Float16*)take(4096UL * 2048 * 2); // cast -> gemm_in; then WoutT
  _Float16* WtH   = (_Float16*)take(8448UL * 2048 * 2); // trans -> gemm_in; then x16
  _Float16* xT16  = (_Float16*)take(4096UL * 4096 * 2); // convx -> states/yfused
  _Float16* B16   = (_Float16*)take(4096UL * 128 * 2);
  _Float16* BT16  = (_Float16*)take(128UL * 4096 * 2);  // convx -> fuse3 (transposed B)
  _Float16* C16   = (_Float16*)take(4096UL * 128 * 2);
  float*    zf    = (float*)take(4096UL * 64 * 4);
  float*    dt_f  = (float*)take(4096UL * 64 * 4);
  float*    cum_f = (float*)take(4096UL * 64 * 4);
  float*    cuml  = (float*)take(16UL * 64 * 4);
  float*    ssq   = (float*)take(4096UL * 4);
  float*    CBT   = (float*)take(16UL * 256 * 256 * 4);  // TRANSPOSED: [bc][j][i]
  float*    states= (float*)take(1024UL * 8192 * 4);    // rparts; states -> prevs; then oparts0
  // overlays:
  float*    rparts = states;              // live gemm_in8..fuse2 (8 x 4MB = 32MB)
  _Float16* WoutT  = Ah;                  // written by fuse2 (after gemm_in8)
  _Float16* x16    = WtH;                 // written by convx (after gemm_in8)
  unsigned short* hid = (unsigned short*)hbcf;  // live yfused..gemm_out8 (33.5MB in 71MB)
  float*    oparts0 = states;             // live gemm_out8..add_out (33.5MB exact)
  float*    oparts1 = (float*)gateh;      // live gemm_out8..add_out (33.5MB exact)

  // 1. prep: dtz || cast || transpose_win (one launch)
  prep<<<26112, 256, 0, stream>>>(hs, Win, Ah, WtH, zf);
  // 2. fp16 in_proj GEMM (256^2 8-phase; square per-XCD regions + remainder)
  gemm_in8<<<dim3(640), 512, 0, stream>>>(Ah, WtH, gateh, hbcf, rparts);
  // 3. fuse2: dt_cum || add_rem || transpose_wout (nw folded) (one launch)
  fuse2<<<9232, 256, 0, stream>>>(zf, dtb, Alog, dt_f, cum_f, cuml,
                                  rparts, hbcf, Wout, nw, WoutT);
  // 4. convx: rolling-tap conv+SiLU fused with x->xT and B->BT transposes
  convx<<<dim3(68, 64), 256, 0, stream>>>(hbcf, convw, convb, x16, B16, C16,
                                          (unsigned short*)xT16,
                                          (unsigned short*)BT16);
  // 5. fuse3: states_mfma (B-frags from BT16) || CBTt gemm || ssq zero
  fuse3<<<1092, 256, 0, stream>>>((const unsigned short*)xT16,
                                  (const unsigned short*)BT16, B16, C16,
                                  dt_f, cum_f, cuml, states, CBT, ssq);
  // 6. inter-chunk recurrence (1024 blocks)
  recur_kernel<<<1024, 256, 0, stream>>>(states, cuml);
  // 7. yfused: Ydiag+Yoff+D*x, *SiLU(gate) -> hid fp16 (un-normalized) + ssq
  yfused<<<dim3(64, 16), 256, 0, stream>>>((const unsigned short*)xT16,
                                           (const unsigned short*)x16,
                                           (const unsigned short*)C16,
                                           (const unsigned short*)gateh,
                                           CBT, states, dt_f, cum_f, Dp,
                                           hid, ssq);
  // 8. out_proj GEMM (256^2 8-phase, split-K z=2) on un-normalized hid
  gemm_out8<<<dim3(256), 512, 0, stream>>>((const _Float16*)hid, WoutT,
                                           oparts0, oparts1);
  // 9. sum partials, apply RMS row-scale -> d_out fp32
  add_out<<<8192, 256, 0, stream>>>(oparts0, oparts1, ssq, out);
}